// Round 9
// baseline (141.496 us; speedup 1.0000x reference)
//
#include <hip/hip_runtime.h>

// ---------------------------------------------------------------------------
// MultiHeadedAttention: x[8,1024,768] @ w_in[768,2304] -> qkv -> 12-head attn
// (scale = 768^-0.5) -> concat -> @ w_out[768,768] + b_out. f32 in/out,
// bf16 MFMA internally. R9: GEMM -> 128x256 tile (wave = 64x128, 32 MFMA per
// barrier-pair) + LDS k-group swizzle via pre-swizzled global source
// (gs = g ^ ((row>>1)&3)) so ds_read_b128 is 2-way-conflict-free.
// Counted-vmcnt 3-buffer 2-deep pipeline kept. Attn unchanged from R7.
// ---------------------------------------------------------------------------

using short8 = __attribute__((ext_vector_type(8))) short;  // 8 bf16 (4 VGPR)
using s16x4  = __attribute__((ext_vector_type(4))) short;  // 4 bf16 (b64)
using f32x4  = __attribute__((ext_vector_type(4))) float;  // MFMA acc

#define MFMA_B16(a, b, c) __builtin_amdgcn_mfma_f32_16x16x32_bf16((a), (b), (c), 0, 0, 0)

typedef const __attribute__((address_space(1))) void* gvoid_p;
typedef __attribute__((address_space(3))) void* lvoid_p;

constexpr int   kDim   = 768;
constexpr int   kHeads = 12;
constexpr int   kSeq   = 1024;
constexpr float kScale = 0.03608439182435161f;             // 768^-0.5 (full dim)
constexpr float kQSc   = kScale * 1.4426950408889634f;     // fold log2(e) into Q

__device__ __forceinline__ short f2bf(float f) {  // RNE f32 -> bf16 bits
  unsigned u = __float_as_uint(f);
  u += 0x7FFFu + ((u >> 16) & 1u);
  return (short)(u >> 16);
}
__device__ __forceinline__ unsigned cvt_pk_bf16(float lo, float hi) {
  unsigned r;
  asm("v_cvt_pk_bf16_f32 %0, %1, %2" : "=v"(r) : "v"(lo), "v"(hi));
  return r;
}
union U8 { unsigned u[4]; short8 s; };

// ---------- x: f32 -> bf16 cast ---------------------------------------------
__global__ __launch_bounds__(256) void cvt_f32_bf16(const float* __restrict__ in,
                                                    short* __restrict__ out) {
  const int i = blockIdx.x * 256 + threadIdx.x;  // one short8 per thread
  float4 a = ((const float4*)in)[i * 2];
  float4 b = ((const float4*)in)[i * 2 + 1];
  short8 s;
  s[0] = f2bf(a.x); s[1] = f2bf(a.y); s[2] = f2bf(a.z); s[3] = f2bf(a.w);
  s[4] = f2bf(b.x); s[5] = f2bf(b.y); s[6] = f2bf(b.z); s[7] = f2bf(b.w);
  ((short8*)out)[i] = s;
}

// ---------- transpose + convert: out[c][r] = bf16(in[r][c]) ----------------
__global__ __launch_bounds__(256) void transpose_cvt(const float* __restrict__ in,
                                                     short* __restrict__ out,
                                                     int R, int C) {
  __shared__ float tile[32][33];
  const int c0 = blockIdx.x * 32, r0 = blockIdx.y * 32;
  const int tx = threadIdx.x & 31, ty = threadIdx.x >> 5;
#pragma unroll
  for (int i = 0; i < 32; i += 8)
    tile[ty + i][tx] = in[(size_t)(r0 + ty + i) * C + c0 + tx];
  __syncthreads();
#pragma unroll
  for (int i = 0; i < 32; i += 8)
    out[(size_t)(c0 + ty + i) * R + r0 + tx] = f2bf(tile[tx][ty + i]);
}

// ---------- 128x256 MFMA GEMM, BK=32, 4 waves (each 64x128) -----------------
// 3-buffer 2-deep counted-vmcnt pipeline. LDS k-group swizzle: element
// (row, k-group g) is stored at group gs = g ^ ((row>>1)&3); gload_lds dest
// stays linear, the SOURCE column is lane-permuted ((l&3)^((l>>3)&3)), and
// ds_read applies the same XOR -> 2-way bank conflicts only (free).
template <int EPI>
__global__ __launch_bounds__(256, 2) void gemm_tile(const short* __restrict__ A,
                                                    const short* __restrict__ BT,
                                                    int Kd,
                                                    short* __restrict__ Qb,
                                                    short* __restrict__ Kb,
                                                    short* __restrict__ VTb,
                                                    const float* __restrict__ bias,
                                                    float* __restrict__ outF) {
  __shared__ short As[3][128 * 32];
  __shared__ short Bs[3][256 * 32];

  const int tid  = threadIdx.x;
  const int lane = tid & 63, w = tid >> 6;
  const int L = lane & 15, g = lane >> 4;
  const int wr = w >> 1, wc = w & 1;        // wave grid 2x2 over 128x256
  const int m0 = blockIdx.x * 128, n0 = blockIdx.y * 256;

  const int srcperm = ((lane & 3) ^ ((lane >> 3) & 3)) * 8;  // source k-col
  const int rdperm  = ((L >> 1) & 3);                        // read-side XOR

  // stage: A 2 issues (32 rows/wave), B 4 issues (64 rows/wave); 6 vmcnt/wave
  auto stage = [&](int buf, int k0) {
#pragma unroll
    for (int c = 0; c < 2; ++c) {
      const short* ag = A + (size_t)(m0 + w * 32 + c * 16 + (lane >> 2)) * Kd + k0 + srcperm;
      __builtin_amdgcn_global_load_lds((gvoid_p)ag, (lvoid_p)&As[buf][w * 1024 + c * 512 + lane * 8], 16, 0, 0);
    }
#pragma unroll
    for (int c = 0; c < 4; ++c) {
      const short* bg = BT + (size_t)(n0 + w * 64 + c * 16 + (lane >> 2)) * Kd + k0 + srcperm;
      __builtin_amdgcn_global_load_lds((gvoid_p)bg, (lvoid_p)&Bs[buf][w * 2048 + c * 512 + lane * 8], 16, 0, 0);
    }
  };

  f32x4 acc[4][8] = {};

  stage(0, 0);
  stage(1, 32);

  const int NT = Kd / 32;
  for (int t = 0; t < NT; ++t) {
    const int cur = t % 3;
    if (t + 2 < NT) stage((t + 2) % 3, (t + 2) * 32);

    // wait for tile t only; newer stages stay in flight across the barrier
    if (t + 2 < NT)      asm volatile("s_waitcnt vmcnt(12)" ::: "memory");
    else if (t + 1 < NT) asm volatile("s_waitcnt vmcnt(6)" ::: "memory");
    else                 asm volatile("s_waitcnt vmcnt(0)" ::: "memory");
    __builtin_amdgcn_s_barrier();  // all waves' tile-t loads landed

    short8 af[4], bfr[8];
#pragma unroll
    for (int mi = 0; mi < 4; ++mi)
      af[mi] = *(const short8*)&As[cur][(wr * 64 + mi * 16 + L) * 32 + (g ^ rdperm) * 8];
#pragma unroll
    for (int ni = 0; ni < 8; ++ni)
      bfr[ni] = *(const short8*)&Bs[cur][(wc * 128 + ni * 16 + L) * 32 + (g ^ rdperm) * 8];
#pragma unroll
    for (int mi = 0; mi < 4; ++mi)
#pragma unroll
      for (int ni = 0; ni < 8; ++ni)
        acc[mi][ni] = MFMA_B16(af[mi], bfr[ni], acc[mi][ni]);

    asm volatile("" ::: "memory");
    __builtin_amdgcn_s_barrier();  // reads done before next stage overwrites
  }

  if (EPI == 0) {
    const int t3 = n0 / kDim;  // 0:Q 1:K 2:V (768 % 256 == 0 -> no straddle)
#pragma unroll
    for (int mi = 0; mi < 4; ++mi) {
#pragma unroll
      for (int ni = 0; ni < 8; ++ni) {
        const int gcol = n0 + wc * 128 + ni * 16 + L;
        const int hd = gcol % kDim;
        const int h = hd >> 6, d = hd & 63;
        if (t3 == 2) {  // V^T: 4 r-values are contiguous seq -> one 8B store
          const int grow = m0 + wr * 64 + mi * 16 + 4 * g;
          const int b = grow >> 10, seq = grow & 1023;
          const int bh = b * kHeads + h;
          uint2 d2;
          d2.x = cvt_pk_bf16(acc[mi][ni][0], acc[mi][ni][1]);
          d2.y = cvt_pk_bf16(acc[mi][ni][2], acc[mi][ni][3]);
          *(uint2*)&VTb[((size_t)bh * 64 + d) * kSeq + seq] = d2;
        } else {
#pragma unroll
          for (int r = 0; r < 4; ++r) {
            const int grow = m0 + wr * 64 + mi * 16 + 4 * g + r;  // b*1024+seq
            const int b = grow >> 10, seq = grow & 1023;
            const int bh = b * kHeads + h;
            if (t3 == 0) Qb[((size_t)bh * kSeq + seq) * 64 + d] = f2bf(acc[mi][ni][r] * kQSc);
            else         Kb[((size_t)bh * kSeq + seq) * 64 + d] = f2bf(acc[mi][ni][r]);
          }
        }
      }
    }
  } else {
#pragma unroll
    for (int ni = 0; ni < 8; ++ni) {
      const int gcol = n0 + wc * 128 + ni * 16 + L;
      const float bv = bias[gcol];
#pragma unroll
      for (int mi = 0; mi < 4; ++mi) {
#pragma unroll
        for (int r = 0; r < 4; ++r) {
          const int grow = m0 + wr * 64 + mi * 16 + 4 * g + r;
          outF[(size_t)grow * kDim + gcol] = acc[mi][ni][r] + bv;
        }
      }
    }
  }
}

// ---------- flash attention (R7, unchanged) ---------------------------------
__global__ __launch_bounds__(256) void attn_kernel(const short* __restrict__ Qb,
                                                   const short* __restrict__ Kb,
                                                   const short* __restrict__ VTb,
                                                   short* __restrict__ AO) {
  __shared__ short Ks[2][64 * 72];   // [key][d]
  __shared__ short VTs[2][64 * 72];  // [d][key]

  const int tid  = threadIdx.x;
  const int lane = tid & 63, w = tid >> 6;
  const int L = lane & 15, g = lane >> 4;
  const int id = blockIdx.x;
  const int bh = id % 96, qc = id / 96;
  const int q0 = qc * 128 + w * 32;

  const short* Qbase = Qb  + (size_t)bh * kSeq * 64;
  const short* Kbase = Kb  + (size_t)bh * kSeq * 64;
  const short* Vbase = VTb + (size_t)bh * 64 * kSeq;

  short8 qf[2][2];  // Q (pre-scaled by kQSc) as B-operand, resident in regs
#pragma unroll
  for (int qh = 0; qh < 2; ++qh) {
    const short* qp = Qbase + (size_t)(q0 + qh * 16 + L) * 64 + g * 8;
    qf[qh][0] = *(const short8*)qp;
    qf[qh][1] = *(const short8*)(qp + 32);
  }

  f32x4 o[2][4] = {};
  float m_[2] = {-1e30f, -1e30f};  // per-query running max (replicated over g)
  float l_[2] = {0.f, 0.f};        // per-LANE partial sum (reduced at end)

  const int srow = tid >> 2, sc0 = (tid & 3) * 16;  // staging: 16 elems/thread

  {  // prologue: stage tile 0
    const short* ksrc = Kbase + (size_t)srow * 64 + sc0;
    const short* vsrc = Vbase + (size_t)srow * kSeq + sc0;
    uint4 k0 = ((const uint4*)ksrc)[0], k1 = ((const uint4*)ksrc)[1];
    uint4 v0 = ((const uint4*)vsrc)[0], v1 = ((const uint4*)vsrc)[1];
    *(uint4*)&Ks[0][srow * 72 + sc0]      = k0;
    *(uint4*)&Ks[0][srow * 72 + sc0 + 8]  = k1;
    *(uint4*)&VTs[0][srow * 72 + sc0]     = v0;
    *(uint4*)&VTs[0][srow * 72 + sc0 + 8] = v1;
  }
  __syncthreads();

  for (int t = 0; t < kSeq / 64; ++t) {
    const int cur = t & 1;
    const bool pf = (t + 1 < kSeq / 64);

    // ---- issue next-tile loads early (T14 async split) ----
    uint4 kr0, kr1, vr0, vr1;
    if (pf) {
      const int kv1 = (t + 1) * 64;
      const short* ksrc = Kbase + (size_t)(kv1 + srow) * 64 + sc0;
      const short* vsrc = Vbase + (size_t)srow * kSeq + kv1 + sc0;
      kr0 = ((const uint4*)ksrc)[0]; kr1 = ((const uint4*)ksrc)[1];
      vr0 = ((const uint4*)vsrc)[0]; vr1 = ((const uint4*)vsrc)[1];
    }

    // ---- K fragments (A-operand) + V fragments (k-perm B-operand) ----
    short8 kf[4][2];
#pragma unroll
    for (int nf = 0; nf < 4; ++nf) {
      const short* kp = &Ks[cur][(nf * 16 + L) * 72 + g * 8];
      kf[nf][0] = *(const short8*)kp;
      kf[nf][1] = *(const short8*)(kp + 32);
    }
    short8 vb[4][2];  // hoisted: ds latency hides under QK + softmax below
#pragma unroll
    for (int nf = 0; nf < 4; ++nf) {
      const short* vrow = &VTs[cur][(nf * 16 + L) * 72];
      s16x4 a0 = *(const s16x4*)&vrow[4 * g];
      s16x4 a1 = *(const s16x4*)&vrow[16 + 4 * g];
      s16x4 a2 = *(const s16x4*)&vrow[32 + 4 * g];
      s16x4 a3 = *(const s16x4*)&vrow[48 + 4 * g];
      vb[nf][0] = __builtin_shufflevector(a0, a1, 0, 1, 2, 3, 4, 5, 6, 7);
      vb[nf][1] = __builtin_shufflevector(a2, a3, 0, 1, 2, 3, 4, 5, 6, 7);
    }

    // ---- BOTH q-halves' S^T = K @ Q^T issued back-to-back (32 MFMAs) ----
    f32x4 s2[2][4];
    __builtin_amdgcn_s_setprio(1);
#pragma unroll
    for (int qh = 0; qh < 2; ++qh) {
#pragma unroll
      for (int nf = 0; nf < 4; ++nf) {
        f32x4 z = {};
        z = MFMA_B16(kf[nf][0], qf[qh][0], z);
        s2[qh][nf] = MFMA_B16(kf[nf][1], qf[qh][1], z);
      }
    }
    __builtin_amdgcn_s_setprio(0);

    // ---- softmax per q-half (lazy max, per-lane l partial, P in regs) ----
    short8 pa[2][2];
#pragma unroll
    for (int qh = 0; qh < 2; ++qh) {
      f32x4* s = s2[qh];
      float x0 = fmaxf(fmaxf(s[0][0], s[0][1]), fmaxf(s[0][2], s[0][3]));
      float x1 = fmaxf(fmaxf(s[1][0], s[1][1]), fmaxf(s[1][2], s[1][3]));
      float x2 = fmaxf(fmaxf(s[2][0], s[2][1]), fmaxf(s[2][2], s[2][3]));
      float x3 = fmaxf(fmaxf(s[3][0], s[3][1]), fmaxf(s[3][2], s[3][3]));
      const float mt4 = fmaxf(fmaxf(x0, x1), fmaxf(x2, x3));

      if (__any(mt4 > m_[qh] + 8.0f)) {  // wave-uniform branch (rare)
        float mt = fmaxf(mt4, __shfl_xor(mt4, 16, 64));
        mt = fmaxf(mt, __shfl_xor(mt, 32, 64));          // per-query true max
        const float mnew = fmaxf(m_[qh], mt);
        const float al = __builtin_amdgcn_exp2f(m_[qh] - mnew);
        m_[qh] = mnew;
        l_[qh] *= al;  // per-lane partial: al is query-uniform across g
        float alr[4];
#pragma unroll
        for (int r = 0; r < 4; ++r) alr[r] = __shfl(al, 4 * g + r, 64);
#pragma unroll
        for (int nf = 0; nf < 4; ++nf)
#pragma unroll
          for (int r = 0; r < 4; ++r) o[qh][nf][r] *= alr[r];
      }

      float rsum = 0.f;
#pragma unroll
      for (int nf = 0; nf < 4; ++nf) {
#pragma unroll
        for (int r = 0; r < 4; ++r) {
          const float p = __builtin_amdgcn_exp2f(s[nf][r] - m_[qh]);
          s[nf][r] = p;
          rsum += p;
        }
      }
      l_[qh] += rsum;  // per-lane partial

      U8 t0, t1;
      t0.u[0] = cvt_pk_bf16(s[0][0], s[0][1]);
      t0.u[1] = cvt_pk_bf16(s[0][2], s[0][3]);
      t0.u[2] = cvt_pk_bf16(s[1][0], s[1][1]);
      t0.u[3] = cvt_pk_bf16(s[1][2], s[1][3]);
      t1.u[0] = cvt_pk_bf16(s[2][0], s[2][1]);
      t1.u[1] = cvt_pk_bf16(s[2][2], s[2][3]);
      t1.u[2] = cvt_pk_bf16(s[3][0], s[3][1]);
      t1.u[3] = cvt_pk_bf16(s[3][2], s[3][3]);
      pa[qh][0] = t0.s;
      pa[qh][1] = t1.s;
    }

    // ---- O += P @ V ----
    __builtin_amdgcn_s_setprio(1);
#pragma unroll
    for (int nf = 0; nf < 4; ++nf) {
#pragma unroll
      for (int qh = 0; qh < 2; ++qh) {
        o[qh][nf] = MFMA_B16(pa[qh][0], vb[nf][0], o[qh][nf]);
        o[qh][nf] = MFMA_B16(pa[qh][1], vb[nf][1], o[qh][nf]);
      }
    }
    __builtin_amdgcn_s_setprio(0);

    // ---- write prefetched tile into other buffer; one barrier per tile ----
    if (pf) {
      *(uint4*)&Ks[cur ^ 1][srow * 72 + sc0]      = kr0;
      *(uint4*)&Ks[cur ^ 1][srow * 72 + sc0 + 8]  = kr1;
      *(uint4*)&VTs[cur ^ 1][srow * 72 + sc0]     = vr0;
      *(uint4*)&VTs[cur ^ 1][srow * 72 + sc0 + 8] = vr1;
    }
    __syncthreads();
  }

  // ---- finalize: reduce l across g-groups ONCE, O /= l, store ----
  const int b = bh / kHeads, h = bh % kHeads;
#pragma unroll
  for (int qh = 0; qh < 2; ++qh) {
    float ls = l_[qh] + __shfl_xor(l_[qh], 16, 64);
    ls += __shfl_xor(ls, 32, 64);  // full per-query sum
    float lq[4];
#pragma unroll
    for (int r = 0; r < 4; ++r) lq[r] = __shfl(ls, 4 * g + r, 64);
    short* aop = AO + ((size_t)(b * kSeq) + q0 + qh * 16) * kDim + h * 64;
#pragma unroll
    for (int r = 0; r < 4; ++r) {
      const float inv = 1.0f / lq[r];
#pragma unroll
      for (int nf = 0; nf < 4; ++nf)
        aop[(size_t)(4 * g + r) * kDim + nf * 16 + L] = f2bf(o[qh][nf][r] * inv);
    }
  }
}

// ---------------------------------------------------------------------------
extern "C" void kernel_launch(void* const* d_in, const int* in_sizes, int n_in,
                              void* d_out, int out_size, void* d_ws, size_t ws_size,
                              hipStream_t stream) {
  const float* x     = (const float*)d_in[0];
  const float* w_in  = (const float*)d_in[1];
  const float* w_out = (const float*)d_in[2];
  const float* b_out = (const float*)d_in[3];
  float* out = (float*)d_out;

  // workspace (bf16 as short). xbf aliases AO: xbf dead before attn writes AO.
  short* WinT  = (short*)d_ws;                          // [2304][768]
  short* WoutT = WinT  + (size_t)2304 * 768;            // [768][768]
  short* Qb    = WoutT + (size_t)768 * 768;             // [96][1024][64]
  short* Kb    = Qb    + (size_t)96 * 1024 * 64;        // [96][1024][64]
  short* VTb   = Kb    + (size_t)96 * 1024 * 64;        // [96][64][1024]
  short* AO    = VTb   + (size_t)96 * 1024 * 64;        // [8192][768]
  short* xbf   = AO;                                    // alias (see above)

  cvt_f32_bf16<<<dim3(8192 * 768 / (256 * 8)), 256, 0, stream>>>(x, xbf);
  transpose_cvt<<<dim3(2304 / 32, 768 / 32), 256, 0, stream>>>(w_in, WinT, 768, 2304);
  transpose_cvt<<<dim3(768 / 32, 768 / 32), 256, 0, stream>>>(w_out, WoutT, 768, 768);

  gemm_tile<0><<<dim3(8192 / 128, 2304 / 256), 256, 0, stream>>>(
      xbf, WinT, 768, Qb, Kb, VTb, nullptr, nullptr);

  attn_kernel<<<dim3(768), 256, 0, stream>>>(Qb, Kb, VTb, AO);

  gemm_tile<1><<<dim3(8192 / 128, 768 / 256), 256, 0, stream>>>(
      AO, WoutT, 768, nullptr, nullptr, nullptr, b_out, out);
}

// Round 10
// 134.743 us; speedup vs baseline: 1.0501x; 1.0501x over previous
//
#include <hip/hip_runtime.h>

// ---------------------------------------------------------------------------
// MultiHeadedAttention: x[8,1024,768] @ w_in[768,2304] -> qkv -> 12-head attn
// (scale = 768^-0.5) -> concat -> @ w_out[768,768] + b_out. f32 in/out,
// bf16 MFMA internally. R10 = R8 GEMM skeleton (128x128, 3-buf counted-vmcnt)
// with the f32->bf16 cast of x FUSED into gemm1's A staging (reg-staged:
// float4 loads issued at loop top for t+2, cvt_pk + ds_write after MFMA).
// Attn unchanged from R7/R8.
// ---------------------------------------------------------------------------

using short8 = __attribute__((ext_vector_type(8))) short;  // 8 bf16 (4 VGPR)
using s16x4  = __attribute__((ext_vector_type(4))) short;  // 4 bf16 (b64)
using f32x4  = __attribute__((ext_vector_type(4))) float;  // MFMA acc

#define MFMA_B16(a, b, c) __builtin_amdgcn_mfma_f32_16x16x32_bf16((a), (b), (c), 0, 0, 0)

typedef const __attribute__((address_space(1))) void* gvoid_p;
typedef __attribute__((address_space(3))) void* lvoid_p;

constexpr int   kDim   = 768;
constexpr int   kHeads = 12;
constexpr int   kSeq   = 1024;
constexpr float kScale = 0.03608439182435161f;             // 768^-0.5 (full dim)
constexpr float kQSc   = kScale * 1.4426950408889634f;     // fold log2(e) into Q

__device__ __forceinline__ short f2bf(float f) {  // RNE f32 -> bf16 bits
  unsigned u = __float_as_uint(f);
  u += 0x7FFFu + ((u >> 16) & 1u);
  return (short)(u >> 16);
}
__device__ __forceinline__ unsigned cvt_pk_bf16(float lo, float hi) {
  unsigned r;
  asm("v_cvt_pk_bf16_f32 %0, %1, %2" : "=v"(r) : "v"(lo), "v"(hi));
  return r;
}
union U8 { unsigned u[4]; short8 s; };

// ---------- transpose + convert: out[c][r] = bf16(in[r][c]) ----------------
__global__ __launch_bounds__(256) void transpose_cvt(const float* __restrict__ in,
                                                     short* __restrict__ out,
                                                     int R, int C) {
  __shared__ float tile[32][33];
  const int c0 = blockIdx.x * 32, r0 = blockIdx.y * 32;
  const int tx = threadIdx.x & 31, ty = threadIdx.x >> 5;
#pragma unroll
  for (int i = 0; i < 32; i += 8)
    tile[ty + i][tx] = in[(size_t)(r0 + ty + i) * C + c0 + tx];
  __syncthreads();
#pragma unroll
  for (int i = 0; i < 32; i += 8)
    out[(size_t)(c0 + ty + i) * R + r0 + tx] = f2bf(tile[tx][ty + i]);
}

// ---------- 128x128 MFMA GEMM, BK=32, 4 waves, 3-buf 2-deep pipeline --------
// AMODE 0: A = f32 source, reg-staged (float4 loads at loop top for t+2,
//          cvt_pk + ds_write_b128 after MFMA; compiler's register-dep waits
//          order everything: waiting on A(t+2) FIFO-drains B(t+1), so B(t)
//          is always landed before its pre-compute barrier).
// AMODE 1: A = bf16, gload_lds staging with counted vmcnt (R8 path, proven).
template <int AMODE, int EPI>
__global__ __launch_bounds__(256) void gemm_tile(const float* __restrict__ Af,
                                                 const short* __restrict__ A,
                                                 const short* __restrict__ BT,
                                                 int Kd,
                                                 short* __restrict__ Qb,
                                                 short* __restrict__ Kb,
                                                 short* __restrict__ VTb,
                                                 const float* __restrict__ bias,
                                                 float* __restrict__ outF) {
  __shared__ short As[3][128 * 32];
  __shared__ short Bs[3][128 * 32];

  const int tid  = threadIdx.x;
  const int lane = tid & 63, w = tid >> 6;
  const int L = lane & 15, g = lane >> 4;
  const int wr = w >> 1, wc = w & 1;
  const int m0 = blockIdx.x * 128, n0 = blockIdx.y * 128;

  const int r4 = lane >> 2;        // row within 16-row chunk (gload_lds)
  const int c8 = (lane & 3) * 8;   // k-col (shorts, gload_lds)

  const int arow = tid >> 1;           // reg-staged A: row 0..127
  const int ac16 = (tid & 1) * 16;     // 16 f32 per thread

  auto stageB = [&](int buf, int k0) {  // 2 gload_lds per wave
#pragma unroll
    for (int c = 0; c < 2; ++c) {
      const short* bg = BT + (size_t)(n0 + w * 32 + c * 16 + r4) * Kd + k0 + c8;
      __builtin_amdgcn_global_load_lds((gvoid_p)bg, (lvoid_p)&Bs[buf][(w * 2 + c) * 512], 16, 0, 0);
    }
  };
  auto stageA1 = [&](int buf, int k0) {  // AMODE=1: 2 gload_lds per wave
#pragma unroll
    for (int c = 0; c < 2; ++c) {
      const short* ag = A + (size_t)(m0 + w * 32 + c * 16 + r4) * Kd + k0 + c8;
      __builtin_amdgcn_global_load_lds((gvoid_p)ag, (lvoid_p)&As[buf][(w * 2 + c) * 512], 16, 0, 0);
    }
  };
  auto cvtWriteA = [&](int buf, const float4& f0, const float4& f1,
                       const float4& f2, const float4& f3) {
    uint4 d0, d1;
    d0.x = cvt_pk_bf16(f0.x, f0.y); d0.y = cvt_pk_bf16(f0.z, f0.w);
    d0.z = cvt_pk_bf16(f1.x, f1.y); d0.w = cvt_pk_bf16(f1.z, f1.w);
    d1.x = cvt_pk_bf16(f2.x, f2.y); d1.y = cvt_pk_bf16(f2.z, f2.w);
    d1.z = cvt_pk_bf16(f3.x, f3.y); d1.w = cvt_pk_bf16(f3.z, f3.w);
    *(uint4*)&As[buf][arow * 32 + ac16]     = d0;
    *(uint4*)&As[buf][arow * 32 + ac16 + 8] = d1;
  };

  f32x4 acc[4][4] = {};
  const int NT = Kd / 32;

  // ---- prologue: tiles 0 and 1 staged ----
  if (AMODE == 0) {
    const float* a0 = Af + (size_t)(m0 + arow) * Kd + 0 + ac16;
    const float* a1 = Af + (size_t)(m0 + arow) * Kd + 32 + ac16;
    float4 p00 = ((const float4*)a0)[0], p01 = ((const float4*)a0)[1];
    float4 p02 = ((const float4*)a0)[2], p03 = ((const float4*)a0)[3];
    float4 p10 = ((const float4*)a1)[0], p11 = ((const float4*)a1)[1];
    float4 p12 = ((const float4*)a1)[2], p13 = ((const float4*)a1)[3];
    stageB(0, 0);
    stageB(1, 32);
    cvtWriteA(0, p00, p01, p02, p03);
    cvtWriteA(1, p10, p11, p12, p13);
    asm volatile("s_waitcnt vmcnt(0) lgkmcnt(0)" ::: "memory");
  } else {
    stageA1(0, 0); stageB(0, 0);
    stageA1(1, 32); stageB(1, 32);
    asm volatile("s_waitcnt vmcnt(0)" ::: "memory");
  }
  __builtin_amdgcn_s_barrier();

  for (int t = 0; t < NT; ++t) {
    const int cur = t % 3;
    const int nxt = (t + 2) % 3;
    const bool pf = (t + 2 < NT);

    float4 f0, f1, f2, f3;
    if (AMODE == 0) {
      if (pf) {  // issue f32 loads for tile t+2 (consumed after MFMA below)
        const float* ap = Af + (size_t)(m0 + arow) * Kd + (t + 2) * 32 + ac16;
        f0 = ((const float4*)ap)[0]; f1 = ((const float4*)ap)[1];
        f2 = ((const float4*)ap)[2]; f3 = ((const float4*)ap)[3];
        stageB(nxt, (t + 2) * 32);
      } else {
        asm volatile("s_waitcnt vmcnt(0)" ::: "memory");  // tail: B landed
      }
    } else {
      if (pf) { stageA1(nxt, (t + 2) * 32); stageB(nxt, (t + 2) * 32); }
      if (t + 2 < NT)      asm volatile("s_waitcnt vmcnt(8)" ::: "memory");
      else if (t + 1 < NT) asm volatile("s_waitcnt vmcnt(4)" ::: "memory");
      else                 asm volatile("s_waitcnt vmcnt(0)" ::: "memory");
    }
    __builtin_amdgcn_s_barrier();  // tile t fully staged for all waves

    short8 af[4], bfr[4];
#pragma unroll
    for (int mi = 0; mi < 4; ++mi)
      af[mi] = *(const short8*)&As[cur][(wr * 64 + mi * 16 + L) * 32 + g * 8];
#pragma unroll
    for (int ni = 0; ni < 4; ++ni)
      bfr[ni] = *(const short8*)&Bs[cur][(wc * 64 + ni * 16 + L) * 32 + g * 8];
#pragma unroll
    for (int mi = 0; mi < 4; ++mi)
#pragma unroll
      for (int ni = 0; ni < 4; ++ni)
        acc[mi][ni] = MFMA_B16(af[mi], bfr[ni], acc[mi][ni]);

    if (AMODE == 0 && pf) {
      cvtWriteA(nxt, f0, f1, f2, f3);  // compiler waits the f32 regs here
      asm volatile("s_waitcnt lgkmcnt(0)" ::: "memory");  // writes visible
    } else {
      asm volatile("" ::: "memory");
    }
    __builtin_amdgcn_s_barrier();  // reads done before next stage overwrites
  }

  if (EPI == 0) {
    const int t3 = n0 / kDim;  // 0:Q 1:K 2:V (uniform per block; 768 = 6*128)
#pragma unroll
    for (int mi = 0; mi < 4; ++mi) {
#pragma unroll
      for (int ni = 0; ni < 4; ++ni) {
        const int gcol = n0 + wc * 64 + ni * 16 + L;
        const int hd = gcol % kDim;
        const int h = hd >> 6, d = hd & 63;
        if (t3 == 2) {  // V^T: 4 r-values are contiguous seq -> one 8B store
          const int grow = m0 + wr * 64 + mi * 16 + 4 * g;
          const int b = grow >> 10, seq = grow & 1023;
          const int bh = b * kHeads + h;
          uint2 d2;
          d2.x = cvt_pk_bf16(acc[mi][ni][0], acc[mi][ni][1]);
          d2.y = cvt_pk_bf16(acc[mi][ni][2], acc[mi][ni][3]);
          *(uint2*)&VTb[((size_t)bh * 64 + d) * kSeq + seq] = d2;
        } else {
#pragma unroll
          for (int r = 0; r < 4; ++r) {
            const int grow = m0 + wr * 64 + mi * 16 + 4 * g + r;  // b*1024+seq
            const int b = grow >> 10, seq = grow & 1023;
            const int bh = b * kHeads + h;
            if (t3 == 0) Qb[((size_t)bh * kSeq + seq) * 64 + d] = f2bf(acc[mi][ni][r] * kQSc);
            else         Kb[((size_t)bh * kSeq + seq) * 64 + d] = f2bf(acc[mi][ni][r]);
          }
        }
      }
    }
  } else {
#pragma unroll
    for (int ni = 0; ni < 4; ++ni) {
      const int gcol = n0 + wc * 64 + ni * 16 + L;
      const float bv = bias[gcol];
#pragma unroll
      for (int mi = 0; mi < 4; ++mi) {
#pragma unroll
        for (int r = 0; r < 4; ++r) {
          const int grow = m0 + wr * 64 + mi * 16 + 4 * g + r;
          outF[(size_t)grow * kDim + gcol] = acc[mi][ni][r] + bv;
        }
      }
    }
  }
}

// ---------- flash attention (R7/R8, unchanged) -------------------------------
__global__ __launch_bounds__(256) void attn_kernel(const short* __restrict__ Qb,
                                                   const short* __restrict__ Kb,
                                                   const short* __restrict__ VTb,
                                                   short* __restrict__ AO) {
  __shared__ short Ks[2][64 * 72];   // [key][d]
  __shared__ short VTs[2][64 * 72];  // [d][key]

  const int tid  = threadIdx.x;
  const int lane = tid & 63, w = tid >> 6;
  const int L = lane & 15, g = lane >> 4;
  const int id = blockIdx.x;
  const int bh = id % 96, qc = id / 96;
  const int q0 = qc * 128 + w * 32;

  const short* Qbase = Qb  + (size_t)bh * kSeq * 64;
  const short* Kbase = Kb  + (size_t)bh * kSeq * 64;
  const short* Vbase = VTb + (size_t)bh * 64 * kSeq;

  short8 qf[2][2];  // Q (pre-scaled by kQSc) as B-operand, resident in regs
#pragma unroll
  for (int qh = 0; qh < 2; ++qh) {
    const short* qp = Qbase + (size_t)(q0 + qh * 16 + L) * 64 + g * 8;
    qf[qh][0] = *(const short8*)qp;
    qf[qh][1] = *(const short8*)(qp + 32);
  }

  f32x4 o[2][4] = {};
  float m_[2] = {-1e30f, -1e30f};  // per-query running max (replicated over g)
  float l_[2] = {0.f, 0.f};        // per-LANE partial sum (reduced at end)

  const int srow = tid >> 2, sc0 = (tid & 3) * 16;  // staging: 16 elems/thread

  {  // prologue: stage tile 0
    const short* ksrc = Kbase + (size_t)srow * 64 + sc0;
    const short* vsrc = Vbase + (size_t)srow * kSeq + sc0;
    uint4 k0 = ((const uint4*)ksrc)[0], k1 = ((const uint4*)ksrc)[1];
    uint4 v0 = ((const uint4*)vsrc)[0], v1 = ((const uint4*)vsrc)[1];
    *(uint4*)&Ks[0][srow * 72 + sc0]      = k0;
    *(uint4*)&Ks[0][srow * 72 + sc0 + 8]  = k1;
    *(uint4*)&VTs[0][srow * 72 + sc0]     = v0;
    *(uint4*)&VTs[0][srow * 72 + sc0 + 8] = v1;
  }
  __syncthreads();

  for (int t = 0; t < kSeq / 64; ++t) {
    const int cur = t & 1;
    const bool pf = (t + 1 < kSeq / 64);

    // ---- issue next-tile loads early (T14 async split) ----
    uint4 kr0, kr1, vr0, vr1;
    if (pf) {
      const int kv1 = (t + 1) * 64;
      const short* ksrc = Kbase + (size_t)(kv1 + srow) * 64 + sc0;
      const short* vsrc = Vbase + (size_t)srow * kSeq + kv1 + sc0;
      kr0 = ((const uint4*)ksrc)[0]; kr1 = ((const uint4*)ksrc)[1];
      vr0 = ((const uint4*)vsrc)[0]; vr1 = ((const uint4*)vsrc)[1];
    }

    // ---- K fragments (A-operand) + V fragments (k-perm B-operand) ----
    short8 kf[4][2];
#pragma unroll
    for (int nf = 0; nf < 4; ++nf) {
      const short* kp = &Ks[cur][(nf * 16 + L) * 72 + g * 8];
      kf[nf][0] = *(const short8*)kp;
      kf[nf][1] = *(const short8*)(kp + 32);
    }
    short8 vb[4][2];  // hoisted: ds latency hides under QK + softmax below
#pragma unroll
    for (int nf = 0; nf < 4; ++nf) {
      const short* vrow = &VTs[cur][(nf * 16 + L) * 72];
      s16x4 a0 = *(const s16x4*)&vrow[4 * g];
      s16x4 a1 = *(const s16x4*)&vrow[16 + 4 * g];
      s16x4 a2 = *(const s16x4*)&vrow[32 + 4 * g];
      s16x4 a3 = *(const s16x4*)&vrow[48 + 4 * g];
      vb[nf][0] = __builtin_shufflevector(a0, a1, 0, 1, 2, 3, 4, 5, 6, 7);
      vb[nf][1] = __builtin_shufflevector(a2, a3, 0, 1, 2, 3, 4, 5, 6, 7);
    }

    // ---- BOTH q-halves' S^T = K @ Q^T issued back-to-back (32 MFMAs) ----
    f32x4 s2[2][4];
    __builtin_amdgcn_s_setprio(1);
#pragma unroll
    for (int qh = 0; qh < 2; ++qh) {
#pragma unroll
      for (int nf = 0; nf < 4; ++nf) {
        f32x4 z = {};
        z = MFMA_B16(kf[nf][0], qf[qh][0], z);
        s2[qh][nf] = MFMA_B16(kf[nf][1], qf[qh][1], z);
      }
    }
    __builtin_amdgcn_s_setprio(0);

    // ---- softmax per q-half (lazy max, per-lane l partial, P in regs) ----
    short8 pa[2][2];
#pragma unroll
    for (int qh = 0; qh < 2; ++qh) {
      f32x4* s = s2[qh];
      float x0 = fmaxf(fmaxf(s[0][0], s[0][1]), fmaxf(s[0][2], s[0][3]));
      float x1 = fmaxf(fmaxf(s[1][0], s[1][1]), fmaxf(s[1][2], s[1][3]));
      float x2 = fmaxf(fmaxf(s[2][0], s[2][1]), fmaxf(s[2][2], s[2][3]));
      float x3 = fmaxf(fmaxf(s[3][0], s[3][1]), fmaxf(s[3][2], s[3][3]));
      const float mt4 = fmaxf(fmaxf(x0, x1), fmaxf(x2, x3));

      if (__any(mt4 > m_[qh] + 8.0f)) {  // wave-uniform branch (rare)
        float mt = fmaxf(mt4, __shfl_xor(mt4, 16, 64));
        mt = fmaxf(mt, __shfl_xor(mt, 32, 64));          // per-query true max
        const float mnew = fmaxf(m_[qh], mt);
        const float al = __builtin_amdgcn_exp2f(m_[qh] - mnew);
        m_[qh] = mnew;
        l_[qh] *= al;  // per-lane partial: al is query-uniform across g
        float alr[4];
#pragma unroll
        for (int r = 0; r < 4; ++r) alr[r] = __shfl(al, 4 * g + r, 64);
#pragma unroll
        for (int nf = 0; nf < 4; ++nf)
#pragma unroll
          for (int r = 0; r < 4; ++r) o[qh][nf][r] *= alr[r];
      }

      float rsum = 0.f;
#pragma unroll
      for (int nf = 0; nf < 4; ++nf) {
#pragma unroll
        for (int r = 0; r < 4; ++r) {
          const float p = __builtin_amdgcn_exp2f(s[nf][r] - m_[qh]);
          s[nf][r] = p;
          rsum += p;
        }
      }
      l_[qh] += rsum;  // per-lane partial

      U8 t0, t1;
      t0.u[0] = cvt_pk_bf16(s[0][0], s[0][1]);
      t0.u[1] = cvt_pk_bf16(s[0][2], s[0][3]);
      t0.u[2] = cvt_pk_bf16(s[1][0], s[1][1]);
      t0.u[3] = cvt_pk_bf16(s[1][2], s[1][3]);
      t1.u[0] = cvt_pk_bf16(s[2][0], s[2][1]);
      t1.u[1] = cvt_pk_bf16(s[2][2], s[2][3]);
      t1.u[2] = cvt_pk_bf16(s[3][0], s[3][1]);
      t1.u[3] = cvt_pk_bf16(s[3][2], s[3][3]);
      pa[qh][0] = t0.s;
      pa[qh][1] = t1.s;
    }

    // ---- O += P @ V ----
    __builtin_amdgcn_s_setprio(1);
#pragma unroll
    for (int nf = 0; nf < 4; ++nf) {
#pragma unroll
      for (int qh = 0; qh < 2; ++qh) {
        o[qh][nf] = MFMA_B16(pa[qh][0], vb[nf][0], o[qh][nf]);
        o[qh][nf] = MFMA_B16(pa[qh][1], vb[nf][1], o[qh][nf]);
      }
    }
    __builtin_amdgcn_s_setprio(0);

    // ---- write prefetched tile into other buffer; one barrier per tile ----
    if (pf) {
      *(uint4*)&Ks[cur ^ 1][srow * 72 + sc0]      = kr0;
      *(uint4*)&Ks[cur ^ 1][srow * 72 + sc0 + 8]  = kr1;
      *(uint4*)&VTs[cur ^ 1][srow * 72 + sc0]     = vr0;
      *(uint4*)&VTs[cur ^ 1][srow * 72 + sc0 + 8] = vr1;
    }
    __syncthreads();
  }

  // ---- finalize: reduce l across g-groups ONCE, O /= l, store ----
  const int b = bh / kHeads, h = bh % kHeads;
#pragma unroll
  for (int qh = 0; qh < 2; ++qh) {
    float ls = l_[qh] + __shfl_xor(l_[qh], 16, 64);
    ls += __shfl_xor(ls, 32, 64);  // full per-query sum
    float lq[4];
#pragma unroll
    for (int r = 0; r < 4; ++r) lq[r] = __shfl(ls, 4 * g + r, 64);
    short* aop = AO + ((size_t)(b * kSeq) + q0 + qh * 16) * kDim + h * 64;
#pragma unroll
    for (int r = 0; r < 4; ++r) {
      const float inv = 1.0f / lq[r];
#pragma unroll
      for (int nf = 0; nf < 4; ++nf)
        aop[(size_t)(4 * g + r) * kDim + nf * 16 + L] = f2bf(o[qh][nf][r] * inv);
    }
  }
}

// ---------------------------------------------------------------------------
extern "C" void kernel_launch(void* const* d_in, const int* in_sizes, int n_in,
                              void* d_out, int out_size, void* d_ws, size_t ws_size,
                              hipStream_t stream) {
  const float* x     = (const float*)d_in[0];
  const float* w_in  = (const float*)d_in[1];
  const float* w_out = (const float*)d_in[2];
  const float* b_out = (const float*)d_in[3];
  float* out = (float*)d_out;

  // workspace (bf16 bits as short)
  short* WinT  = (short*)d_ws;                          // [2304][768]
  short* WoutT = WinT  + (size_t)2304 * 768;            // [768][768]
  short* Qb    = WoutT + (size_t)768 * 768;             // [96][1024][64]
  short* Kb    = Qb    + (size_t)96 * 1024 * 64;        // [96][1024][64]
  short* VTb   = Kb    + (size_t)96 * 1024 * 64;        // [96][64][1024]
  short* AO    = VTb   + (size_t)96 * 1024 * 64;        // [8192][768]

  transpose_cvt<<<dim3(2304 / 32, 768 / 32), 256, 0, stream>>>(w_in, WinT, 768, 2304);
  transpose_cvt<<<dim3(768 / 32, 768 / 32), 256, 0, stream>>>(w_out, WoutT, 768, 768);

  // gemm1: A = x (f32, cast fused into staging)
  gemm_tile<0, 0><<<dim3(8192 / 128, 2304 / 128), 256, 0, stream>>>(
      x, nullptr, WinT, 768, Qb, Kb, VTb, nullptr, nullptr);

  attn_kernel<<<dim3(768), 256, 0, stream>>>(Qb, Kb, VTb, AO);

  // gemm2: A = AO (bf16, gload_lds path)
  gemm_tile<1, 1><<<dim3(8192 / 128, 768 / 128), 256, 0, stream>>>(
      nullptr, AO, WoutT, 768, nullptr, nullptr, nullptr, b_out, out);
}

// Round 11
// 130.619 us; speedup vs baseline: 1.0833x; 1.0316x over previous
//
#include <hip/hip_runtime.h>

// ---------------------------------------------------------------------------
// MultiHeadedAttention: x[8,1024,768] @ w_in[768,2304] -> qkv -> 12-head attn
// (scale = 768^-0.5) -> concat -> @ w_out[768,768] + b_out. f32 in/out,
// bf16 MFMA internally. R11 = R8 GEMM skeleton (proven best) + single merged
// prep kernel (cast + both weight transposes) + attn q-tile 64 (16 rows/wave,
// grid 1536) to raise occupancy on the VALU-bound softmax.
// ---------------------------------------------------------------------------

using short8 = __attribute__((ext_vector_type(8))) short;  // 8 bf16 (4 VGPR)
using s16x4  = __attribute__((ext_vector_type(4))) short;  // 4 bf16 (b64)
using f32x4  = __attribute__((ext_vector_type(4))) float;  // MFMA acc

#define MFMA_B16(a, b, c) __builtin_amdgcn_mfma_f32_16x16x32_bf16((a), (b), (c), 0, 0, 0)

typedef const __attribute__((address_space(1))) void* gvoid_p;
typedef __attribute__((address_space(3))) void* lvoid_p;

constexpr int   kDim   = 768;
constexpr int   kHeads = 12;
constexpr int   kSeq   = 1024;
constexpr float kScale = 0.03608439182435161f;             // 768^-0.5 (full dim)
constexpr float kQSc   = kScale * 1.4426950408889634f;     // fold log2(e) into Q

__device__ __forceinline__ short f2bf(float f) {  // RNE f32 -> bf16 bits
  unsigned u = __float_as_uint(f);
  u += 0x7FFFu + ((u >> 16) & 1u);
  return (short)(u >> 16);
}
__device__ __forceinline__ unsigned cvt_pk_bf16(float lo, float hi) {
  unsigned r;
  asm("v_cvt_pk_bf16_f32 %0, %1, %2" : "=v"(r) : "v"(lo), "v"(hi));
  return r;
}
union U8 { unsigned u[4]; short8 s; };

// ---------- merged prep: x cast (blocks 0..3071), w_in^T (next 1728),
// ----------              w_out^T (last 576). One launch instead of three.
__global__ __launch_bounds__(256) void prep_kernel(const float* __restrict__ x,
                                                   short* __restrict__ xbf,
                                                   const float* __restrict__ w_in,
                                                   short* __restrict__ WinT,
                                                   const float* __restrict__ w_out,
                                                   short* __restrict__ WoutT) {
  __shared__ float tile[32][33];
  const int bid = blockIdx.x;
  if (bid < 3072) {  // cast: one short8 per thread
    const int i = bid * 256 + threadIdx.x;
    float4 a = ((const float4*)x)[i * 2];
    float4 b = ((const float4*)x)[i * 2 + 1];
    short8 s;
    s[0] = f2bf(a.x); s[1] = f2bf(a.y); s[2] = f2bf(a.z); s[3] = f2bf(a.w);
    s[4] = f2bf(b.x); s[5] = f2bf(b.y); s[6] = f2bf(b.z); s[7] = f2bf(b.w);
    ((short8*)xbf)[i] = s;
    return;
  }
  // transpose+cvt: out[c][r] = bf16(in[r][c])
  const float* in; short* out; int R, C, bx, by;
  if (bid < 3072 + 1728) {
    const int b2 = bid - 3072;
    in = w_in; out = WinT; R = 768; C = 2304; bx = b2 % 72; by = b2 / 72;
  } else {
    const int b2 = bid - 4800;
    in = w_out; out = WoutT; R = 768; C = 768; bx = b2 % 24; by = b2 / 24;
  }
  const int c0 = bx * 32, r0 = by * 32;
  const int tx = threadIdx.x & 31, ty = threadIdx.x >> 5;
#pragma unroll
  for (int i = 0; i < 32; i += 8)
    tile[ty + i][tx] = in[(size_t)(r0 + ty + i) * C + c0 + tx];
  __syncthreads();
#pragma unroll
  for (int i = 0; i < 32; i += 8)
    out[(size_t)(c0 + ty + i) * R + r0 + tx] = f2bf(tile[tx][ty + i]);
}

// ---------- 128x128 MFMA GEMM, BK=32, 4 waves, 3-buf 2-deep counted-vmcnt --
// (exact R8 structure — best measured; do not touch)
template <int EPI>
__global__ __launch_bounds__(256) void gemm_tile(const short* __restrict__ A,
                                                 const short* __restrict__ BT,
                                                 int Kd,
                                                 short* __restrict__ Qb,
                                                 short* __restrict__ Kb,
                                                 short* __restrict__ VTb,
                                                 const float* __restrict__ bias,
                                                 float* __restrict__ outF) {
  __shared__ short As[3][128 * 32];
  __shared__ short Bs[3][128 * 32];

  const int tid  = threadIdx.x;
  const int lane = tid & 63, w = tid >> 6;
  const int L = lane & 15, g = lane >> 4;
  const int wr = w >> 1, wc = w & 1;
  const int m0 = blockIdx.x * 128, n0 = blockIdx.y * 128;

  const int r4 = lane >> 2;        // row within 16-row chunk
  const int c8 = (lane & 3) * 8;   // k-col (shorts)

  auto stage = [&](int buf, int k0) {  // 4 gload_lds per wave (vmcnt +4)
#pragma unroll
    for (int c = 0; c < 2; ++c) {
      const short* ag = A  + (size_t)(m0 + w * 32 + c * 16 + r4) * Kd + k0 + c8;
      const short* bg = BT + (size_t)(n0 + w * 32 + c * 16 + r4) * Kd + k0 + c8;
      __builtin_amdgcn_global_load_lds((gvoid_p)ag, (lvoid_p)&As[buf][(w * 2 + c) * 512], 16, 0, 0);
      __builtin_amdgcn_global_load_lds((gvoid_p)bg, (lvoid_p)&Bs[buf][(w * 2 + c) * 512], 16, 0, 0);
    }
  };

  f32x4 acc[4][4] = {};

  stage(0, 0);
  stage(1, 32);

  const int NT = Kd / 32;
  for (int t = 0; t < NT; ++t) {
    const int cur = t % 3;
    if (t + 2 < NT) stage((t + 2) % 3, (t + 2) * 32);

    // wait for tile t only; tiles t+1, t+2 (8 loads) stay in flight
    if (t + 2 < NT)      asm volatile("s_waitcnt vmcnt(8)" ::: "memory");
    else if (t + 1 < NT) asm volatile("s_waitcnt vmcnt(4)" ::: "memory");
    else                 asm volatile("s_waitcnt vmcnt(0)" ::: "memory");
    __builtin_amdgcn_s_barrier();  // all waves' tile-t loads landed

    short8 af[4], bfr[4];
#pragma unroll
    for (int mi = 0; mi < 4; ++mi)
      af[mi] = *(const short8*)&As[cur][(wr * 64 + mi * 16 + L) * 32 + g * 8];
#pragma unroll
    for (int ni = 0; ni < 4; ++ni)
      bfr[ni] = *(const short8*)&Bs[cur][(wc * 64 + ni * 16 + L) * 32 + g * 8];
#pragma unroll
    for (int mi = 0; mi < 4; ++mi)
#pragma unroll
      for (int ni = 0; ni < 4; ++ni)
        acc[mi][ni] = MFMA_B16(af[mi], bfr[ni], acc[mi][ni]);

    asm volatile("" ::: "memory");
    __builtin_amdgcn_s_barrier();  // reads done before next stage overwrites
  }

  if (EPI == 0) {
    const int t3 = n0 / kDim;  // 0:Q 1:K 2:V (uniform per block; 768 = 6*128)
#pragma unroll
    for (int mi = 0; mi < 4; ++mi) {
#pragma unroll
      for (int ni = 0; ni < 4; ++ni) {
        const int gcol = n0 + wc * 64 + ni * 16 + L;
        const int hd = gcol % kDim;
        const int h = hd >> 6, d = hd & 63;
        if (t3 == 2) {  // V^T: 4 r-values are contiguous seq -> one 8B store
          const int grow = m0 + wr * 64 + mi * 16 + 4 * g;
          const int b = grow >> 10, seq = grow & 1023;
          const int bh = b * kHeads + h;
          uint2 d2;
          d2.x = cvt_pk_bf16(acc[mi][ni][0], acc[mi][ni][1]);
          d2.y = cvt_pk_bf16(acc[mi][ni][2], acc[mi][ni][3]);
          *(uint2*)&VTb[((size_t)bh * 64 + d) * kSeq + seq] = d2;
        } else {
#pragma unroll
          for (int r = 0; r < 4; ++r) {
            const int grow = m0 + wr * 64 + mi * 16 + 4 * g + r;  // b*1024+seq
            const int b = grow >> 10, seq = grow & 1023;
            const int bh = b * kHeads + h;
            if (t3 == 0) Qb[((size_t)bh * kSeq + seq) * 64 + d] = f2bf(acc[mi][ni][r] * kQSc);
            else         Kb[((size_t)bh * kSeq + seq) * 64 + d] = f2bf(acc[mi][ni][r]);
          }
        }
      }
    }
  } else {
#pragma unroll
    for (int ni = 0; ni < 4; ++ni) {
      const int gcol = n0 + wc * 64 + ni * 16 + L;
      const float bv = bias[gcol];
#pragma unroll
      for (int mi = 0; mi < 4; ++mi) {
#pragma unroll
        for (int r = 0; r < 4; ++r) {
          const int grow = m0 + wr * 64 + mi * 16 + 4 * g + r;
          outF[(size_t)grow * kDim + gcol] = acc[mi][ni][r] + bv;
        }
      }
    }
  }
}

// ---------- flash attention v8: q-tile 64 (16 rows/wave), grid 1536 ---------
// Same per-tile machinery as R7/R8 (swapped QK^T, k-perm PV, P in regs, lazy
// max, deferred l-reduce, K+V LDS dbuf, T14 split, 1 barrier/tile) but each
// wave owns 16 q-rows -> 2x blocks -> 4 blocks/CU resident (LDS-capped),
// raising TLP on the VALU-bound softmax. id%8 == bh%8 (96 % 8 == 0).
__global__ __launch_bounds__(256) void attn_kernel(const short* __restrict__ Qb,
                                                   const short* __restrict__ Kb,
                                                   const short* __restrict__ VTb,
                                                   short* __restrict__ AO) {
  __shared__ short Ks[2][64 * 72];   // [key][d]
  __shared__ short VTs[2][64 * 72];  // [d][key]

  const int tid  = threadIdx.x;
  const int lane = tid & 63, w = tid >> 6;
  const int L = lane & 15, g = lane >> 4;
  const int id = blockIdx.x;
  const int bh = id % 96, qc = id / 96;   // qc in 0..15
  const int q0 = qc * 64 + w * 16;

  const short* Qbase = Qb  + (size_t)bh * kSeq * 64;
  const short* Kbase = Kb  + (size_t)bh * kSeq * 64;
  const short* Vbase = VTb + (size_t)bh * 64 * kSeq;

  short8 qf[2];  // Q (pre-scaled by kQSc) as B-operand, resident in regs
  {
    const short* qp = Qbase + (size_t)(q0 + L) * 64 + g * 8;
    qf[0] = *(const short8*)qp;
    qf[1] = *(const short8*)(qp + 32);
  }

  f32x4 o[4] = {};
  float m_ = -1e30f;  // per-query running max (replicated over g)
  float l_ = 0.f;     // per-LANE partial sum (reduced at finalize)

  const int srow = tid >> 2, sc0 = (tid & 3) * 16;  // staging: 16 elems/thread

  {  // prologue: stage tile 0
    const short* ksrc = Kbase + (size_t)srow * 64 + sc0;
    const short* vsrc = Vbase + (size_t)srow * kSeq + sc0;
    uint4 k0 = ((const uint4*)ksrc)[0], k1 = ((const uint4*)ksrc)[1];
    uint4 v0 = ((const uint4*)vsrc)[0], v1 = ((const uint4*)vsrc)[1];
    *(uint4*)&Ks[0][srow * 72 + sc0]      = k0;
    *(uint4*)&Ks[0][srow * 72 + sc0 + 8]  = k1;
    *(uint4*)&VTs[0][srow * 72 + sc0]     = v0;
    *(uint4*)&VTs[0][srow * 72 + sc0 + 8] = v1;
  }
  __syncthreads();

  for (int t = 0; t < kSeq / 64; ++t) {
    const int cur = t & 1;
    const bool pf = (t + 1 < kSeq / 64);

    // ---- issue next-tile loads early (T14 async split) ----
    uint4 kr0, kr1, vr0, vr1;
    if (pf) {
      const int kv1 = (t + 1) * 64;
      const short* ksrc = Kbase + (size_t)(kv1 + srow) * 64 + sc0;
      const short* vsrc = Vbase + (size_t)srow * kSeq + kv1 + sc0;
      kr0 = ((const uint4*)ksrc)[0]; kr1 = ((const uint4*)ksrc)[1];
      vr0 = ((const uint4*)vsrc)[0]; vr1 = ((const uint4*)vsrc)[1];
    }

    // ---- K fragments (A-operand) + V fragments (k-perm B-operand) ----
    short8 kf[4][2];
#pragma unroll
    for (int nf = 0; nf < 4; ++nf) {
      const short* kp = &Ks[cur][(nf * 16 + L) * 72 + g * 8];
      kf[nf][0] = *(const short8*)kp;
      kf[nf][1] = *(const short8*)(kp + 32);
    }
    short8 vb[4][2];  // hoisted: ds latency hides under QK + softmax below
#pragma unroll
    for (int nf = 0; nf < 4; ++nf) {
      const short* vrow = &VTs[cur][(nf * 16 + L) * 72];
      s16x4 a0 = *(const s16x4*)&vrow[4 * g];
      s16x4 a1 = *(const s16x4*)&vrow[16 + 4 * g];
      s16x4 a2 = *(const s16x4*)&vrow[32 + 4 * g];
      s16x4 a3 = *(const s16x4*)&vrow[48 + 4 * g];
      vb[nf][0] = __builtin_shufflevector(a0, a1, 0, 1, 2, 3, 4, 5, 6, 7);
      vb[nf][1] = __builtin_shufflevector(a2, a3, 0, 1, 2, 3, 4, 5, 6, 7);
    }

    // ---- S^T = K @ Q^T: lane holds S[key=nf*16+4g+r][query=L] ----
    f32x4 s[4];
    __builtin_amdgcn_s_setprio(1);
#pragma unroll
    for (int nf = 0; nf < 4; ++nf) {
      f32x4 z = {};
      z = MFMA_B16(kf[nf][0], qf[0], z);
      s[nf] = MFMA_B16(kf[nf][1], qf[1], z);
    }
    __builtin_amdgcn_s_setprio(0);

    // ---- lazy defer-max: per-lane max only on common path ----
    float x0 = fmaxf(fmaxf(s[0][0], s[0][1]), fmaxf(s[0][2], s[0][3]));
    float x1 = fmaxf(fmaxf(s[1][0], s[1][1]), fmaxf(s[1][2], s[1][3]));
    float x2 = fmaxf(fmaxf(s[2][0], s[2][1]), fmaxf(s[2][2], s[2][3]));
    float x3 = fmaxf(fmaxf(s[3][0], s[3][1]), fmaxf(s[3][2], s[3][3]));
    const float mt4 = fmaxf(fmaxf(x0, x1), fmaxf(x2, x3));

    if (__any(mt4 > m_ + 8.0f)) {  // wave-uniform branch (rare)
      float mt = fmaxf(mt4, __shfl_xor(mt4, 16, 64));
      mt = fmaxf(mt, __shfl_xor(mt, 32, 64));          // per-query true max
      const float mnew = fmaxf(m_, mt);
      const float al = __builtin_amdgcn_exp2f(m_ - mnew);
      m_ = mnew;
      l_ *= al;  // per-lane partial: al is query-uniform across g
      float alr[4];
#pragma unroll
      for (int r = 0; r < 4; ++r) alr[r] = __shfl(al, 4 * g + r, 64);
#pragma unroll
      for (int nf = 0; nf < 4; ++nf)
#pragma unroll
        for (int r = 0; r < 4; ++r) o[nf][r] *= alr[r];
    }

    // ---- p = exp2(s - m); lane-local sum; P packed in regs ----
    float rsum = 0.f;
#pragma unroll
    for (int nf = 0; nf < 4; ++nf) {
#pragma unroll
      for (int r = 0; r < 4; ++r) {
        const float p = __builtin_amdgcn_exp2f(s[nf][r] - m_);
        s[nf][r] = p;
        rsum += p;
      }
    }
    l_ += rsum;  // per-lane partial

    short8 pa0, pa1;
    {
      U8 t0, t1;
      t0.u[0] = cvt_pk_bf16(s[0][0], s[0][1]);
      t0.u[1] = cvt_pk_bf16(s[0][2], s[0][3]);
      t0.u[2] = cvt_pk_bf16(s[1][0], s[1][1]);
      t0.u[3] = cvt_pk_bf16(s[1][2], s[1][3]);
      t1.u[0] = cvt_pk_bf16(s[2][0], s[2][1]);
      t1.u[1] = cvt_pk_bf16(s[2][2], s[2][3]);
      t1.u[2] = cvt_pk_bf16(s[3][0], s[3][1]);
      t1.u[3] = cvt_pk_bf16(s[3][2], s[3][3]);
      pa0 = t0.s;
      pa1 = t1.s;
    }

    // ---- O += P @ V ----
    __builtin_amdgcn_s_setprio(1);
#pragma unroll
    for (int nf = 0; nf < 4; ++nf) {
      o[nf] = MFMA_B16(pa0, vb[nf][0], o[nf]);
      o[nf] = MFMA_B16(pa1, vb[nf][1], o[nf]);
    }
    __builtin_amdgcn_s_setprio(0);

    // ---- write prefetched tile into other buffer; one barrier per tile ----
    if (pf) {
      *(uint4*)&Ks[cur ^ 1][srow * 72 + sc0]      = kr0;
      *(uint4*)&Ks[cur ^ 1][srow * 72 + sc0 + 8]  = kr1;
      *(uint4*)&VTs[cur ^ 1][srow * 72 + sc0]     = vr0;
      *(uint4*)&VTs[cur ^ 1][srow * 72 + sc0 + 8] = vr1;
    }
    __syncthreads();
  }

  // ---- finalize: reduce l across g-groups ONCE, O /= l, store ----
  const int b = bh / kHeads, h = bh % kHeads;
  float ls = l_ + __shfl_xor(l_, 16, 64);
  ls += __shfl_xor(ls, 32, 64);  // full per-query sum
  float lq[4];
#pragma unroll
  for (int r = 0; r < 4; ++r) lq[r] = __shfl(ls, 4 * g + r, 64);
  short* aop = AO + ((size_t)(b * kSeq) + q0) * kDim + h * 64;
#pragma unroll
  for (int r = 0; r < 4; ++r) {
    const float inv = 1.0f / lq[r];
#pragma unroll
    for (int nf = 0; nf < 4; ++nf)
      aop[(size_t)(4 * g + r) * kDim + nf * 16 + L] = f2bf(o[nf][r] * inv);
  }
}

// ---------------------------------------------------------------------------
extern "C" void kernel_launch(void* const* d_in, const int* in_sizes, int n_in,
                              void* d_out, int out_size, void* d_ws, size_t ws_size,
                              hipStream_t stream) {
  const float* x     = (const float*)d_in[0];
  const float* w_in  = (const float*)d_in[1];
  const float* w_out = (const float*)d_in[2];
  const float* b_out = (const float*)d_in[3];
  float* out = (float*)d_out;

  // workspace (bf16 as short). xbf aliases AO: xbf dead before attn writes AO.
  short* WinT  = (short*)d_ws;                          // [2304][768]
  short* WoutT = WinT  + (size_t)2304 * 768;            // [768][768]
  short* Qb    = WoutT + (size_t)768 * 768;             // [96][1024][64]
  short* Kb    = Qb    + (size_t)96 * 1024 * 64;        // [96][1024][64]
  short* VTb   = Kb    + (size_t)96 * 1024 * 64;        // [96][64][1024]
  short* AO    = VTb   + (size_t)96 * 1024 * 64;        // [8192][768]
  short* xbf   = AO;                                    // alias (see above)

  prep_kernel<<<dim3(3072 + 1728 + 576), 256, 0, stream>>>(
      x, xbf, w_in, WinT, w_out, WoutT);

  gemm_tile<0><<<dim3(8192 / 128, 2304 / 128), 256, 0, stream>>>(
      xbf, WinT, 768, Qb, Kb, VTb, nullptr, nullptr);

  attn_kernel<<<dim3(1536), 256, 0, stream>>>(Qb, Kb, VTb, AO);

  gemm_tile<1><<<dim3(8192 / 128, 768 / 128), 256, 0, stream>>>(
      AO, WoutT, 768, nullptr, nullptr, nullptr, b_out, out);
}

// Round 12
// 122.059 us; speedup vs baseline: 1.1592x; 1.0701x over previous
//
#include <hip/hip_runtime.h>

// ---------------------------------------------------------------------------
// MultiHeadedAttention: x[8,1024,768] @ w_in[768,2304] -> qkv -> 12-head attn
// (scale = 768^-0.5) -> concat -> @ w_out[768,768] + b_out. f32 in/out,
// bf16 MFMA internally. R12 = consolidated best: R8 GEMM (128x128, 3-buf
// 2-deep counted-vmcnt), R8 attn (q-tile 128, K+V LDS dbuf, swapped QK^T,
// P-in-regs, lazy max), single merged prep kernel (cast + both transposes).
// ---------------------------------------------------------------------------

using short8 = __attribute__((ext_vector_type(8))) short;  // 8 bf16 (4 VGPR)
using s16x4  = __attribute__((ext_vector_type(4))) short;  // 4 bf16 (b64)
using f32x4  = __attribute__((ext_vector_type(4))) float;  // MFMA acc

#define MFMA_B16(a, b, c) __builtin_amdgcn_mfma_f32_16x16x32_bf16((a), (b), (c), 0, 0, 0)

typedef const __attribute__((address_space(1))) void* gvoid_p;
typedef __attribute__((address_space(3))) void* lvoid_p;

constexpr int   kDim   = 768;
constexpr int   kHeads = 12;
constexpr int   kSeq   = 1024;
constexpr float kScale = 0.03608439182435161f;             // 768^-0.5 (full dim)
constexpr float kQSc   = kScale * 1.4426950408889634f;     // fold log2(e) into Q

__device__ __forceinline__ short f2bf(float f) {  // RNE f32 -> bf16 bits
  unsigned u = __float_as_uint(f);
  u += 0x7FFFu + ((u >> 16) & 1u);
  return (short)(u >> 16);
}
__device__ __forceinline__ unsigned cvt_pk_bf16(float lo, float hi) {
  unsigned r;
  asm("v_cvt_pk_bf16_f32 %0, %1, %2" : "=v"(r) : "v"(lo), "v"(hi));
  return r;
}
union U8 { unsigned u[4]; short8 s; };

// ---------- merged prep: x cast (blocks 0..3071), w_in^T (next 1728),
// ----------              w_out^T (last 576). One launch instead of three.
__global__ __launch_bounds__(256) void prep_kernel(const float* __restrict__ x,
                                                   short* __restrict__ xbf,
                                                   const float* __restrict__ w_in,
                                                   short* __restrict__ WinT,
                                                   const float* __restrict__ w_out,
                                                   short* __restrict__ WoutT) {
  __shared__ float tile[32][33];
  const int bid = blockIdx.x;
  if (bid < 3072) {  // cast: one short8 per thread
    const int i = bid * 256 + threadIdx.x;
    float4 a = ((const float4*)x)[i * 2];
    float4 b = ((const float4*)x)[i * 2 + 1];
    short8 s;
    s[0] = f2bf(a.x); s[1] = f2bf(a.y); s[2] = f2bf(a.z); s[3] = f2bf(a.w);
    s[4] = f2bf(b.x); s[5] = f2bf(b.y); s[6] = f2bf(b.z); s[7] = f2bf(b.w);
    ((short8*)xbf)[i] = s;
    return;
  }
  // transpose+cvt: out[c][r] = bf16(in[r][c])
  const float* in; short* out; int R, C, bx, by;
  if (bid < 3072 + 1728) {
    const int b2 = bid - 3072;
    in = w_in; out = WinT; R = 768; C = 2304; bx = b2 % 72; by = b2 / 72;
  } else {
    const int b2 = bid - 4800;
    in = w_out; out = WoutT; R = 768; C = 768; bx = b2 % 24; by = b2 / 24;
  }
  const int c0 = bx * 32, r0 = by * 32;
  const int tx = threadIdx.x & 31, ty = threadIdx.x >> 5;
#pragma unroll
  for (int i = 0; i < 32; i += 8)
    tile[ty + i][tx] = in[(size_t)(r0 + ty + i) * C + c0 + tx];
  __syncthreads();
#pragma unroll
  for (int i = 0; i < 32; i += 8)
    out[(size_t)(c0 + ty + i) * R + r0 + tx] = f2bf(tile[tx][ty + i]);
}

// ---------- 128x128 MFMA GEMM, BK=32, 4 waves, 3-buf 2-deep counted-vmcnt --
// (exact R8 structure — measured best; do not touch)
template <int EPI>
__global__ __launch_bounds__(256) void gemm_tile(const short* __restrict__ A,
                                                 const short* __restrict__ BT,
                                                 int Kd,
                                                 short* __restrict__ Qb,
                                                 short* __restrict__ Kb,
                                                 short* __restrict__ VTb,
                                                 const float* __restrict__ bias,
                                                 float* __restrict__ outF) {
  __shared__ short As[3][128 * 32];
  __shared__ short Bs[3][128 * 32];

  const int tid  = threadIdx.x;
  const int lane = tid & 63, w = tid >> 6;
  const int L = lane & 15, g = lane >> 4;
  const int wr = w >> 1, wc = w & 1;
  const int m0 = blockIdx.x * 128, n0 = blockIdx.y * 128;

  const int r4 = lane >> 2;        // row within 16-row chunk
  const int c8 = (lane & 3) * 8;   // k-col (shorts)

  auto stage = [&](int buf, int k0) {  // 4 gload_lds per wave (vmcnt +4)
#pragma unroll
    for (int c = 0; c < 2; ++c) {
      const short* ag = A  + (size_t)(m0 + w * 32 + c * 16 + r4) * Kd + k0 + c8;
      const short* bg = BT + (size_t)(n0 + w * 32 + c * 16 + r4) * Kd + k0 + c8;
      __builtin_amdgcn_global_load_lds((gvoid_p)ag, (lvoid_p)&As[buf][(w * 2 + c) * 512], 16, 0, 0);
      __builtin_amdgcn_global_load_lds((gvoid_p)bg, (lvoid_p)&Bs[buf][(w * 2 + c) * 512], 16, 0, 0);
    }
  };

  f32x4 acc[4][4] = {};

  stage(0, 0);
  stage(1, 32);

  const int NT = Kd / 32;
  for (int t = 0; t < NT; ++t) {
    const int cur = t % 3;
    if (t + 2 < NT) stage((t + 2) % 3, (t + 2) * 32);

    // wait for tile t only; tiles t+1, t+2 (8 loads) stay in flight
    if (t + 2 < NT)      asm volatile("s_waitcnt vmcnt(8)" ::: "memory");
    else if (t + 1 < NT) asm volatile("s_waitcnt vmcnt(4)" ::: "memory");
    else                 asm volatile("s_waitcnt vmcnt(0)" ::: "memory");
    __builtin_amdgcn_s_barrier();  // all waves' tile-t loads landed

    short8 af[4], bfr[4];
#pragma unroll
    for (int mi = 0; mi < 4; ++mi)
      af[mi] = *(const short8*)&As[cur][(wr * 64 + mi * 16 + L) * 32 + g * 8];
#pragma unroll
    for (int ni = 0; ni < 4; ++ni)
      bfr[ni] = *(const short8*)&Bs[cur][(wc * 64 + ni * 16 + L) * 32 + g * 8];
#pragma unroll
    for (int mi = 0; mi < 4; ++mi)
#pragma unroll
      for (int ni = 0; ni < 4; ++ni)
        acc[mi][ni] = MFMA_B16(af[mi], bfr[ni], acc[mi][ni]);

    asm volatile("" ::: "memory");
    __builtin_amdgcn_s_barrier();  // reads done before next stage overwrites
  }

  if (EPI == 0) {
    const int t3 = n0 / kDim;  // 0:Q 1:K 2:V (uniform per block; 768 = 6*128)
#pragma unroll
    for (int mi = 0; mi < 4; ++mi) {
#pragma unroll
      for (int ni = 0; ni < 4; ++ni) {
        const int gcol = n0 + wc * 64 + ni * 16 + L;
        const int hd = gcol % kDim;
        const int h = hd >> 6, d = hd & 63;
        if (t3 == 2) {  // V^T: 4 r-values are contiguous seq -> one 8B store
          const int grow = m0 + wr * 64 + mi * 16 + 4 * g;
          const int b = grow >> 10, seq = grow & 1023;
          const int bh = b * kHeads + h;
          uint2 d2;
          d2.x = cvt_pk_bf16(acc[mi][ni][0], acc[mi][ni][1]);
          d2.y = cvt_pk_bf16(acc[mi][ni][2], acc[mi][ni][3]);
          *(uint2*)&VTb[((size_t)bh * 64 + d) * kSeq + seq] = d2;
        } else {
#pragma unroll
          for (int r = 0; r < 4; ++r) {
            const int grow = m0 + wr * 64 + mi * 16 + 4 * g + r;  // b*1024+seq
            const int b = grow >> 10, seq = grow & 1023;
            const int bh = b * kHeads + h;
            if (t3 == 0) Qb[((size_t)bh * kSeq + seq) * 64 + d] = f2bf(acc[mi][ni][r] * kQSc);
            else         Kb[((size_t)bh * kSeq + seq) * 64 + d] = f2bf(acc[mi][ni][r]);
          }
        }
      }
    }
  } else {
#pragma unroll
    for (int ni = 0; ni < 4; ++ni) {
      const int gcol = n0 + wc * 64 + ni * 16 + L;
      const float bv = bias[gcol];
#pragma unroll
      for (int mi = 0; mi < 4; ++mi) {
#pragma unroll
        for (int r = 0; r < 4; ++r) {
          const int grow = m0 + wr * 64 + mi * 16 + 4 * g + r;
          outF[(size_t)grow * kDim + gcol] = acc[mi][ni][r] + bv;
        }
      }
    }
  }
}

// ---------- flash attention (exact R8 structure — measured best) ------------
__global__ __launch_bounds__(256) void attn_kernel(const short* __restrict__ Qb,
                                                   const short* __restrict__ Kb,
                                                   const short* __restrict__ VTb,
                                                   short* __restrict__ AO) {
  __shared__ short Ks[2][64 * 72];   // [key][d]
  __shared__ short VTs[2][64 * 72];  // [d][key]

  const int tid  = threadIdx.x;
  const int lane = tid & 63, w = tid >> 6;
  const int L = lane & 15, g = lane >> 4;
  const int id = blockIdx.x;
  const int bh = id % 96, qc = id / 96;
  const int q0 = qc * 128 + w * 32;

  const short* Qbase = Qb  + (size_t)bh * kSeq * 64;
  const short* Kbase = Kb  + (size_t)bh * kSeq * 64;
  const short* Vbase = VTb + (size_t)bh * 64 * kSeq;

  short8 qf[2][2];  // Q (pre-scaled by kQSc) as B-operand, resident in regs
#pragma unroll
  for (int qh = 0; qh < 2; ++qh) {
    const short* qp = Qbase + (size_t)(q0 + qh * 16 + L) * 64 + g * 8;
    qf[qh][0] = *(const short8*)qp;
    qf[qh][1] = *(const short8*)(qp + 32);
  }

  f32x4 o[2][4] = {};
  float m_[2] = {-1e30f, -1e30f};  // per-query running max (replicated over g)
  float l_[2] = {0.f, 0.f};        // per-LANE partial sum (reduced at end)

  const int srow = tid >> 2, sc0 = (tid & 3) * 16;  // staging: 16 elems/thread

  {  // prologue: stage tile 0
    const short* ksrc = Kbase + (size_t)srow * 64 + sc0;
    const short* vsrc = Vbase + (size_t)srow * kSeq + sc0;
    uint4 k0 = ((const uint4*)ksrc)[0], k1 = ((const uint4*)ksrc)[1];
    uint4 v0 = ((const uint4*)vsrc)[0], v1 = ((const uint4*)vsrc)[1];
    *(uint4*)&Ks[0][srow * 72 + sc0]      = k0;
    *(uint4*)&Ks[0][srow * 72 + sc0 + 8]  = k1;
    *(uint4*)&VTs[0][srow * 72 + sc0]     = v0;
    *(uint4*)&VTs[0][srow * 72 + sc0 + 8] = v1;
  }
  __syncthreads();

  for (int t = 0; t < kSeq / 64; ++t) {
    const int cur = t & 1;
    const bool pf = (t + 1 < kSeq / 64);

    // ---- issue next-tile loads early (T14 async split) ----
    uint4 kr0, kr1, vr0, vr1;
    if (pf) {
      const int kv1 = (t + 1) * 64;
      const short* ksrc = Kbase + (size_t)(kv1 + srow) * 64 + sc0;
      const short* vsrc = Vbase + (size_t)srow * kSeq + kv1 + sc0;
      kr0 = ((const uint4*)ksrc)[0]; kr1 = ((const uint4*)ksrc)[1];
      vr0 = ((const uint4*)vsrc)[0]; vr1 = ((const uint4*)vsrc)[1];
    }

    // ---- K fragments (A-operand) + V fragments (k-perm B-operand) ----
    short8 kf[4][2];
#pragma unroll
    for (int nf = 0; nf < 4; ++nf) {
      const short* kp = &Ks[cur][(nf * 16 + L) * 72 + g * 8];
      kf[nf][0] = *(const short8*)kp;
      kf[nf][1] = *(const short8*)(kp + 32);
    }
    short8 vb[4][2];  // hoisted: ds latency hides under QK + softmax below
#pragma unroll
    for (int nf = 0; nf < 4; ++nf) {
      const short* vrow = &VTs[cur][(nf * 16 + L) * 72];
      s16x4 a0 = *(const s16x4*)&vrow[4 * g];
      s16x4 a1 = *(const s16x4*)&vrow[16 + 4 * g];
      s16x4 a2 = *(const s16x4*)&vrow[32 + 4 * g];
      s16x4 a3 = *(const s16x4*)&vrow[48 + 4 * g];
      vb[nf][0] = __builtin_shufflevector(a0, a1, 0, 1, 2, 3, 4, 5, 6, 7);
      vb[nf][1] = __builtin_shufflevector(a2, a3, 0, 1, 2, 3, 4, 5, 6, 7);
    }

    // ---- BOTH q-halves' S^T = K @ Q^T issued back-to-back (32 MFMAs) ----
    f32x4 s2[2][4];
    __builtin_amdgcn_s_setprio(1);
#pragma unroll
    for (int qh = 0; qh < 2; ++qh) {
#pragma unroll
      for (int nf = 0; nf < 4; ++nf) {
        f32x4 z = {};
        z = MFMA_B16(kf[nf][0], qf[qh][0], z);
        s2[qh][nf] = MFMA_B16(kf[nf][1], qf[qh][1], z);
      }
    }
    __builtin_amdgcn_s_setprio(0);

    // ---- softmax per q-half (lazy max, per-lane l partial, P in regs) ----
    short8 pa[2][2];
#pragma unroll
    for (int qh = 0; qh < 2; ++qh) {
      f32x4* s = s2[qh];
      float x0 = fmaxf(fmaxf(s[0][0], s[0][1]), fmaxf(s[0][2], s[0][3]));
      float x1 = fmaxf(fmaxf(s[1][0], s[1][1]), fmaxf(s[1][2], s[1][3]));
      float x2 = fmaxf(fmaxf(s[2][0], s[2][1]), fmaxf(s[2][2], s[2][3]));
      float x3 = fmaxf(fmaxf(s[3][0], s[3][1]), fmaxf(s[3][2], s[3][3]));
      const float mt4 = fmaxf(fmaxf(x0, x1), fmaxf(x2, x3));

      if (__any(mt4 > m_[qh] + 8.0f)) {  // wave-uniform branch (rare)
        float mt = fmaxf(mt4, __shfl_xor(mt4, 16, 64));
        mt = fmaxf(mt, __shfl_xor(mt, 32, 64));          // per-query true max
        const float mnew = fmaxf(m_[qh], mt);
        const float al = __builtin_amdgcn_exp2f(m_[qh] - mnew);
        m_[qh] = mnew;
        l_[qh] *= al;  // per-lane partial: al is query-uniform across g
        float alr[4];
#pragma unroll
        for (int r = 0; r < 4; ++r) alr[r] = __shfl(al, 4 * g + r, 64);
#pragma unroll
        for (int nf = 0; nf < 4; ++nf)
#pragma unroll
          for (int r = 0; r < 4; ++r) o[qh][nf][r] *= alr[r];
      }

      float rsum = 0.f;
#pragma unroll
      for (int nf = 0; nf < 4; ++nf) {
#pragma unroll
        for (int r = 0; r < 4; ++r) {
          const float p = __builtin_amdgcn_exp2f(s[nf][r] - m_[qh]);
          s[nf][r] = p;
          rsum += p;
        }
      }
      l_[qh] += rsum;  // per-lane partial

      U8 t0, t1;
      t0.u[0] = cvt_pk_bf16(s[0][0], s[0][1]);
      t0.u[1] = cvt_pk_bf16(s[0][2], s[0][3]);
      t0.u[2] = cvt_pk_bf16(s[1][0], s[1][1]);
      t0.u[3] = cvt_pk_bf16(s[1][2], s[1][3]);
      t1.u[0] = cvt_pk_bf16(s[2][0], s[2][1]);
      t1.u[1] = cvt_pk_bf16(s[2][2], s[2][3]);
      t1.u[2] = cvt_pk_bf16(s[3][0], s[3][1]);
      t1.u[3] = cvt_pk_bf16(s[3][2], s[3][3]);
      pa[qh][0] = t0.s;
      pa[qh][1] = t1.s;
    }

    // ---- O += P @ V ----
    __builtin_amdgcn_s_setprio(1);
#pragma unroll
    for (int nf = 0; nf < 4; ++nf) {
#pragma unroll
      for (int qh = 0; qh < 2; ++qh) {
        o[qh][nf] = MFMA_B16(pa[qh][0], vb[nf][0], o[qh][nf]);
        o[qh][nf] = MFMA_B16(pa[qh][1], vb[nf][1], o[qh][nf]);
      }
    }
    __builtin_amdgcn_s_setprio(0);

    // ---- write prefetched tile into other buffer; one barrier per tile ----
    if (pf) {
      *(uint4*)&Ks[cur ^ 1][srow * 72 + sc0]      = kr0;
      *(uint4*)&Ks[cur ^ 1][srow * 72 + sc0 + 8]  = kr1;
      *(uint4*)&VTs[cur ^ 1][srow * 72 + sc0]     = vr0;
      *(uint4*)&VTs[cur ^ 1][srow * 72 + sc0 + 8] = vr1;
    }
    __syncthreads();
  }

  // ---- finalize: reduce l across g-groups ONCE, O /= l, store ----
  const int b = bh / kHeads, h = bh % kHeads;
#pragma unroll
  for (int qh = 0; qh < 2; ++qh) {
    float ls = l_[qh] + __shfl_xor(l_[qh], 16, 64);
    ls += __shfl_xor(ls, 32, 64);  // full per-query sum
    float lq[4];
#pragma unroll
    for (int r = 0; r < 4; ++r) lq[r] = __shfl(ls, 4 * g + r, 64);
    short* aop = AO + ((size_t)(b * kSeq) + q0 + qh * 16) * kDim + h * 64;
#pragma unroll
    for (int r = 0; r < 4; ++r) {
      const float inv = 1.0f / lq[r];
#pragma unroll
      for (int nf = 0; nf < 4; ++nf)
        aop[(size_t)(4 * g + r) * kDim + nf * 16 + L] = f2bf(o[qh][nf][r] * inv);
    }
  }
}

// ---------------------------------------------------------------------------
extern "C" void kernel_launch(void* const* d_in, const int* in_sizes, int n_in,
                              void* d_out, int out_size, void* d_ws, size_t ws_size,
                              hipStream_t stream) {
  const float* x     = (const float*)d_in[0];
  const float* w_in  = (const float*)d_in[1];
  const float* w_out = (const float*)d_in[2];
  const float* b_out = (const float*)d_in[3];
  float* out = (float*)d_out;

  // workspace (bf16 as short). xbf aliases AO: xbf dead before attn writes AO.
  short* WinT  = (short*)d_ws;                          // [2304][768]
  short* WoutT = WinT  + (size_t)2304 * 768;            // [768][768]
  short* Qb    = WoutT + (size_t)768 * 768;             // [96][1024][64]
  short* Kb    = Qb    + (size_t)96 * 1024 * 64;        // [96][1024][64]
  short* VTb   = Kb    + (size_t)96 * 1024 * 64;        // [96][64][1024]
  short* AO    = VTb   + (size_t)96 * 1024 * 64;        // [8192][768]
  short* xbf   = AO;                                    // alias (see above)

  prep_kernel<<<dim3(3072 + 1728 + 576), 256, 0, stream>>>(
      x, xbf, w_in, WinT, w_out, WoutT);

  gemm_tile<0><<<dim3(8192 / 128, 2304 / 128), 256, 0, stream>>>(
      xbf, WinT, 768, Qb, Kb, VTb, nullptr, nullptr);

  attn_kernel<<<dim3(768), 256, 0, stream>>>(Qb, Kb, VTb, AO);

  gemm_tile<1><<<dim3(8192 / 128, 768 / 128), 256, 0, stream>>>(
      AO, WoutT, 768, nullptr, nullptr, nullptr, b_out, out);
}

// Round 13
// 120.161 us; speedup vs baseline: 1.1776x; 1.0158x over previous
//
#include <hip/hip_runtime.h>

// ---------------------------------------------------------------------------
// MultiHeadedAttention: x[8,1024,768] @ w_in[768,2304] -> qkv -> 12-head attn
// (scale = 768^-0.5) -> concat -> @ w_out[768,768] + b_out. f32 in/out,
// bf16 MFMA internally. R13 = R12 + key-permuted V^T layout: gemm1's epilogue
// stores each 64-key block in the PV k-perm order (p = 32(s>>5)+8((s>>2)&3)
// +4((s>>4)&1)+(s&3)), so attn's V B-fragments are 2x ds_read_b128 per nf
// (8/tile/wave) instead of 32x ds_read_b64.
// ---------------------------------------------------------------------------

using short8 = __attribute__((ext_vector_type(8))) short;  // 8 bf16 (4 VGPR)
using f32x4  = __attribute__((ext_vector_type(4))) float;  // MFMA acc

#define MFMA_B16(a, b, c) __builtin_amdgcn_mfma_f32_16x16x32_bf16((a), (b), (c), 0, 0, 0)

typedef const __attribute__((address_space(1))) void* gvoid_p;
typedef __attribute__((address_space(3))) void* lvoid_p;

constexpr int   kDim   = 768;
constexpr int   kHeads = 12;
constexpr int   kSeq   = 1024;
constexpr float kScale = 0.03608439182435161f;             // 768^-0.5 (full dim)
constexpr float kQSc   = kScale * 1.4426950408889634f;     // fold log2(e) into Q

__device__ __forceinline__ short f2bf(float f) {  // RNE f32 -> bf16 bits
  unsigned u = __float_as_uint(f);
  u += 0x7FFFu + ((u >> 16) & 1u);
  return (short)(u >> 16);
}
__device__ __forceinline__ unsigned cvt_pk_bf16(float lo, float hi) {
  unsigned r;
  asm("v_cvt_pk_bf16_f32 %0, %1, %2" : "=v"(r) : "v"(lo), "v"(hi));
  return r;
}
union U8 { unsigned u[4]; short8 s; };

// ---------- merged prep: x cast (blocks 0..3071), w_in^T (next 1728),
// ----------              w_out^T (last 576). One launch instead of three.
__global__ __launch_bounds__(256) void prep_kernel(const float* __restrict__ x,
                                                   short* __restrict__ xbf,
                                                   const float* __restrict__ w_in,
                                                   short* __restrict__ WinT,
                                                   const float* __restrict__ w_out,
                                                   short* __restrict__ WoutT) {
  __shared__ float tile[32][33];
  const int bid = blockIdx.x;
  if (bid < 3072) {  // cast: one short8 per thread
    const int i = bid * 256 + threadIdx.x;
    float4 a = ((const float4*)x)[i * 2];
    float4 b = ((const float4*)x)[i * 2 + 1];
    short8 s;
    s[0] = f2bf(a.x); s[1] = f2bf(a.y); s[2] = f2bf(a.z); s[3] = f2bf(a.w);
    s[4] = f2bf(b.x); s[5] = f2bf(b.y); s[6] = f2bf(b.z); s[7] = f2bf(b.w);
    ((short8*)xbf)[i] = s;
    return;
  }
  // transpose+cvt: out[c][r] = bf16(in[r][c])
  const float* in; short* out; int R, C, bx, by;
  if (bid < 3072 + 1728) {
    const int b2 = bid - 3072;
    in = w_in; out = WinT; R = 768; C = 2304; bx = b2 % 72; by = b2 / 72;
  } else {
    const int b2 = bid - 4800;
    in = w_out; out = WoutT; R = 768; C = 768; bx = b2 % 24; by = b2 / 24;
  }
  const int c0 = bx * 32, r0 = by * 32;
  const int tx = threadIdx.x & 31, ty = threadIdx.x >> 5;
#pragma unroll
  for (int i = 0; i < 32; i += 8)
    tile[ty + i][tx] = in[(size_t)(r0 + ty + i) * C + c0 + tx];
  __syncthreads();
#pragma unroll
  for (int i = 0; i < 32; i += 8)
    out[(size_t)(c0 + ty + i) * R + r0 + tx] = f2bf(tile[tx][ty + i]);
}

// ---------- 128x128 MFMA GEMM, BK=32, 4 waves, 3-buf 2-deep counted-vmcnt --
// (exact R8/R12 structure — measured best; only the V^T store order changed)
template <int EPI>
__global__ __launch_bounds__(256) void gemm_tile(const short* __restrict__ A,
                                                 const short* __restrict__ BT,
                                                 int Kd,
                                                 short* __restrict__ Qb,
                                                 short* __restrict__ Kb,
                                                 short* __restrict__ VTb,
                                                 const float* __restrict__ bias,
                                                 float* __restrict__ outF) {
  __shared__ short As[3][128 * 32];
  __shared__ short Bs[3][128 * 32];

  const int tid  = threadIdx.x;
  const int lane = tid & 63, w = tid >> 6;
  const int L = lane & 15, g = lane >> 4;
  const int wr = w >> 1, wc = w & 1;
  const int m0 = blockIdx.x * 128, n0 = blockIdx.y * 128;

  const int r4 = lane >> 2;        // row within 16-row chunk
  const int c8 = (lane & 3) * 8;   // k-col (shorts)

  auto stage = [&](int buf, int k0) {  // 4 gload_lds per wave (vmcnt +4)
#pragma unroll
    for (int c = 0; c < 2; ++c) {
      const short* ag = A  + (size_t)(m0 + w * 32 + c * 16 + r4) * Kd + k0 + c8;
      const short* bg = BT + (size_t)(n0 + w * 32 + c * 16 + r4) * Kd + k0 + c8;
      __builtin_amdgcn_global_load_lds((gvoid_p)ag, (lvoid_p)&As[buf][(w * 2 + c) * 512], 16, 0, 0);
      __builtin_amdgcn_global_load_lds((gvoid_p)bg, (lvoid_p)&Bs[buf][(w * 2 + c) * 512], 16, 0, 0);
    }
  };

  f32x4 acc[4][4] = {};

  stage(0, 0);
  stage(1, 32);

  const int NT = Kd / 32;
  for (int t = 0; t < NT; ++t) {
    const int cur = t % 3;
    if (t + 2 < NT) stage((t + 2) % 3, (t + 2) * 32);

    // wait for tile t only; tiles t+1, t+2 (8 loads) stay in flight
    if (t + 2 < NT)      asm volatile("s_waitcnt vmcnt(8)" ::: "memory");
    else if (t + 1 < NT) asm volatile("s_waitcnt vmcnt(4)" ::: "memory");
    else                 asm volatile("s_waitcnt vmcnt(0)" ::: "memory");
    __builtin_amdgcn_s_barrier();  // all waves' tile-t loads landed

    short8 af[4], bfr[4];
#pragma unroll
    for (int mi = 0; mi < 4; ++mi)
      af[mi] = *(const short8*)&As[cur][(wr * 64 + mi * 16 + L) * 32 + g * 8];
#pragma unroll
    for (int ni = 0; ni < 4; ++ni)
      bfr[ni] = *(const short8*)&Bs[cur][(wc * 64 + ni * 16 + L) * 32 + g * 8];
#pragma unroll
    for (int mi = 0; mi < 4; ++mi)
#pragma unroll
      for (int ni = 0; ni < 4; ++ni)
        acc[mi][ni] = MFMA_B16(af[mi], bfr[ni], acc[mi][ni]);

    asm volatile("" ::: "memory");
    __builtin_amdgcn_s_barrier();  // reads done before next stage overwrites
  }

  if (EPI == 0) {
    const int t3 = n0 / kDim;  // 0:Q 1:K 2:V (uniform per block; 768 = 6*128)
#pragma unroll
    for (int mi = 0; mi < 4; ++mi) {
#pragma unroll
      for (int ni = 0; ni < 4; ++ni) {
        const int gcol = n0 + wc * 64 + ni * 16 + L;
        const int hd = gcol % kDim;
        const int h = hd >> 6, d = hd & 63;
        if (t3 == 2) {
          // V^T with key-permuted 64-blocks: position p stores key s where
          // p = 32(s>>5) + 8((s>>2)&3) + 4((s>>4)&1) + (s&3). The 4 r-values
          // are consecutive keys (s%4==0) -> consecutive positions -> 8B store.
          const int grow = m0 + wr * 64 + mi * 16 + 4 * g;
          const int b = grow >> 10, seq = grow & 1023;
          const int bh = b * kHeads + h;
          const int s6 = seq & 63;  // multiple of 4
          const int p  = 32 * (s6 >> 5) + 8 * ((s6 >> 2) & 3) + 4 * ((s6 >> 4) & 1);
          const int seqp = (seq & ~63) | p;
          uint2 d2;
          d2.x = cvt_pk_bf16(acc[mi][ni][0], acc[mi][ni][1]);
          d2.y = cvt_pk_bf16(acc[mi][ni][2], acc[mi][ni][3]);
          *(uint2*)&VTb[((size_t)bh * 64 + d) * kSeq + seqp] = d2;
        } else {
#pragma unroll
          for (int r = 0; r < 4; ++r) {
            const int grow = m0 + wr * 64 + mi * 16 + 4 * g + r;  // b*1024+seq
            const int b = grow >> 10, seq = grow & 1023;
            const int bh = b * kHeads + h;
            if (t3 == 0) Qb[((size_t)bh * kSeq + seq) * 64 + d] = f2bf(acc[mi][ni][r] * kQSc);
            else         Kb[((size_t)bh * kSeq + seq) * 64 + d] = f2bf(acc[mi][ni][r]);
          }
        }
      }
    }
  } else {
#pragma unroll
    for (int ni = 0; ni < 4; ++ni) {
      const int gcol = n0 + wc * 64 + ni * 16 + L;
      const float bv = bias[gcol];
#pragma unroll
      for (int mi = 0; mi < 4; ++mi) {
#pragma unroll
        for (int r = 0; r < 4; ++r) {
          const int grow = m0 + wr * 64 + mi * 16 + 4 * g + r;
          outF[(size_t)grow * kDim + gcol] = acc[mi][ni][r] + bv;
        }
      }
    }
  }
}

// ---------- flash attention (R12 structure; V frags now 2x b128 per nf) -----
__global__ __launch_bounds__(256) void attn_kernel(const short* __restrict__ Qb,
                                                   const short* __restrict__ Kb,
                                                   const short* __restrict__ VTb,
                                                   short* __restrict__ AO) {
  __shared__ short Ks[2][64 * 72];   // [key][d]
  __shared__ short VTs[2][64 * 72];  // [d][key-permuted]

  const int tid  = threadIdx.x;
  const int lane = tid & 63, w = tid >> 6;
  const int L = lane & 15, g = lane >> 4;
  const int id = blockIdx.x;
  const int bh = id % 96, qc = id / 96;
  const int q0 = qc * 128 + w * 32;

  const short* Qbase = Qb  + (size_t)bh * kSeq * 64;
  const short* Kbase = Kb  + (size_t)bh * kSeq * 64;
  const short* Vbase = VTb + (size_t)bh * 64 * kSeq;

  short8 qf[2][2];  // Q (pre-scaled by kQSc) as B-operand, resident in regs
#pragma unroll
  for (int qh = 0; qh < 2; ++qh) {
    const short* qp = Qbase + (size_t)(q0 + qh * 16 + L) * 64 + g * 8;
    qf[qh][0] = *(const short8*)qp;
    qf[qh][1] = *(const short8*)(qp + 32);
  }

  f32x4 o[2][4] = {};
  float m_[2] = {-1e30f, -1e30f};  // per-query running max (replicated over g)
  float l_[2] = {0.f, 0.f};        // per-LANE partial sum (reduced at end)

  const int srow = tid >> 2, sc0 = (tid & 3) * 16;  // staging: 16 elems/thread

  {  // prologue: stage tile 0 (V rows copied verbatim — perm is within blocks)
    const short* ksrc = Kbase + (size_t)srow * 64 + sc0;
    const short* vsrc = Vbase + (size_t)srow * kSeq + sc0;
    uint4 k0 = ((const uint4*)ksrc)[0], k1 = ((const uint4*)ksrc)[1];
    uint4 v0 = ((const uint4*)vsrc)[0], v1 = ((const uint4*)vsrc)[1];
    *(uint4*)&Ks[0][srow * 72 + sc0]      = k0;
    *(uint4*)&Ks[0][srow * 72 + sc0 + 8]  = k1;
    *(uint4*)&VTs[0][srow * 72 + sc0]     = v0;
    *(uint4*)&VTs[0][srow * 72 + sc0 + 8] = v1;
  }
  __syncthreads();

  for (int t = 0; t < kSeq / 64; ++t) {
    const int cur = t & 1;
    const bool pf = (t + 1 < kSeq / 64);

    // ---- issue next-tile loads early (T14 async split) ----
    uint4 kr0, kr1, vr0, vr1;
    if (pf) {
      const int kv1 = (t + 1) * 64;
      const short* ksrc = Kbase + (size_t)(kv1 + srow) * 64 + sc0;
      const short* vsrc = Vbase + (size_t)srow * kSeq + kv1 + sc0;
      kr0 = ((const uint4*)ksrc)[0]; kr1 = ((const uint4*)ksrc)[1];
      vr0 = ((const uint4*)vsrc)[0]; vr1 = ((const uint4*)vsrc)[1];
    }

    // ---- K fragments (A-operand) + V fragments (B-operand, pre-permuted) --
    short8 kf[4][2];
#pragma unroll
    for (int nf = 0; nf < 4; ++nf) {
      const short* kp = &Ks[cur][(nf * 16 + L) * 72 + g * 8];
      kf[nf][0] = *(const short8*)kp;
      kf[nf][1] = *(const short8*)(kp + 32);
    }
    short8 vb[4][2];  // hoisted: ds latency hides under QK + softmax below
#pragma unroll
    for (int nf = 0; nf < 4; ++nf) {
      const short* vrow = &VTs[cur][(nf * 16 + L) * 72];
      vb[nf][0] = *(const short8*)&vrow[g * 8];        // keys {4g..}, {16+4g..}
      vb[nf][1] = *(const short8*)&vrow[32 + g * 8];   // +32 variants
    }

    // ---- BOTH q-halves' S^T = K @ Q^T issued back-to-back (32 MFMAs) ----
    f32x4 s2[2][4];
    __builtin_amdgcn_s_setprio(1);
#pragma unroll
    for (int qh = 0; qh < 2; ++qh) {
#pragma unroll
      for (int nf = 0; nf < 4; ++nf) {
        f32x4 z = {};
        z = MFMA_B16(kf[nf][0], qf[qh][0], z);
        s2[qh][nf] = MFMA_B16(kf[nf][1], qf[qh][1], z);
      }
    }
    __builtin_amdgcn_s_setprio(0);

    // ---- softmax per q-half (lazy max, per-lane l partial, P in regs) ----
    short8 pa[2][2];
#pragma unroll
    for (int qh = 0; qh < 2; ++qh) {
      f32x4* s = s2[qh];
      float x0 = fmaxf(fmaxf(s[0][0], s[0][1]), fmaxf(s[0][2], s[0][3]));
      float x1 = fmaxf(fmaxf(s[1][0], s[1][1]), fmaxf(s[1][2], s[1][3]));
      float x2 = fmaxf(fmaxf(s[2][0], s[2][1]), fmaxf(s[2][2], s[2][3]));
      float x3 = fmaxf(fmaxf(s[3][0], s[3][1]), fmaxf(s[3][2], s[3][3]));
      const float mt4 = fmaxf(fmaxf(x0, x1), fmaxf(x2, x3));

      if (__any(mt4 > m_[qh] + 8.0f)) {  // wave-uniform branch (rare)
        float mt = fmaxf(mt4, __shfl_xor(mt4, 16, 64));
        mt = fmaxf(mt, __shfl_xor(mt, 32, 64));          // per-query true max
        const float mnew = fmaxf(m_[qh], mt);
        const float al = __builtin_amdgcn_exp2f(m_[qh] - mnew);
        m_[qh] = mnew;
        l_[qh] *= al;  // per-lane partial: al is query-uniform across g
        float alr[4];
#pragma unroll
        for (int r = 0; r < 4; ++r) alr[r] = __shfl(al, 4 * g + r, 64);
#pragma unroll
        for (int nf = 0; nf < 4; ++nf)
#pragma unroll
          for (int r = 0; r < 4; ++r) o[qh][nf][r] *= alr[r];
      }

      float rsum = 0.f;
#pragma unroll
      for (int nf = 0; nf < 4; ++nf) {
#pragma unroll
        for (int r = 0; r < 4; ++r) {
          const float p = __builtin_amdgcn_exp2f(s[nf][r] - m_[qh]);
          s[nf][r] = p;
          rsum += p;
        }
      }
      l_[qh] += rsum;  // per-lane partial

      U8 t0, t1;
      t0.u[0] = cvt_pk_bf16(s[0][0], s[0][1]);
      t0.u[1] = cvt_pk_bf16(s[0][2], s[0][3]);
      t0.u[2] = cvt_pk_bf16(s[1][0], s[1][1]);
      t0.u[3] = cvt_pk_bf16(s[1][2], s[1][3]);
      t1.u[0] = cvt_pk_bf16(s[2][0], s[2][1]);
      t1.u[1] = cvt_pk_bf16(s[2][2], s[2][3]);
      t1.u[2] = cvt_pk_bf16(s[3][0], s[3][1]);
      t1.u[3] = cvt_pk_bf16(s[3][2], s[3][3]);
      pa[qh][0] = t0.s;
      pa[qh][1] = t1.s;
    }

    // ---- O += P @ V ----
    __builtin_amdgcn_s_setprio(1);
#pragma unroll
    for (int nf = 0; nf < 4; ++nf) {
#pragma unroll
      for (int qh = 0; qh < 2; ++qh) {
        o[qh][nf] = MFMA_B16(pa[qh][0], vb[nf][0], o[qh][nf]);
        o[qh][nf] = MFMA_B16(pa[qh][1], vb[nf][1], o[qh][nf]);
      }
    }
    __builtin_amdgcn_s_setprio(0);

    // ---- write prefetched tile into other buffer; one barrier per tile ----
    if (pf) {
      *(uint4*)&Ks[cur ^ 1][srow * 72 + sc0]      = kr0;
      *(uint4*)&Ks[cur ^ 1][srow * 72 + sc0 + 8]  = kr1;
      *(uint4*)&VTs[cur ^ 1][srow * 72 + sc0]     = vr0;
      *(uint4*)&VTs[cur ^ 1][srow * 72 + sc0 + 8] = vr1;
    }
    __syncthreads();
  }

  // ---- finalize: reduce l across g-groups ONCE, O /= l, store ----
  const int b = bh / kHeads, h = bh % kHeads;
#pragma unroll
  for (int qh = 0; qh < 2; ++qh) {
    float ls = l_[qh] + __shfl_xor(l_[qh], 16, 64);
    ls += __shfl_xor(ls, 32, 64);  // full per-query sum
    float lq[4];
#pragma unroll
    for (int r = 0; r < 4; ++r) lq[r] = __shfl(ls, 4 * g + r, 64);
    short* aop = AO + ((size_t)(b * kSeq) + q0 + qh * 16) * kDim + h * 64;
#pragma unroll
    for (int r = 0; r < 4; ++r) {
      const float inv = 1.0f / lq[r];
#pragma unroll
      for (int nf = 0; nf < 4; ++nf)
        aop[(size_t)(4 * g + r) * kDim + nf * 16 + L] = f2bf(o[qh][nf][r] * inv);
    }
  }
}

// ---------------------------------------------------------------------------
extern "C" void kernel_launch(void* const* d_in, const int* in_sizes, int n_in,
                              void* d_out, int out_size, void* d_ws, size_t ws_size,
                              hipStream_t stream) {
  const float* x     = (const float*)d_in[0];
  const float* w_in  = (const float*)d_in[1];
  const float* w_out = (const float*)d_in[2];
  const float* b_out = (const float*)d_in[3];
  float* out = (float*)d_out;

  // workspace (bf16 as short). xbf aliases AO: xbf dead before attn writes AO.
  short* WinT  = (short*)d_ws;                          // [2304][768]
  short* WoutT = WinT  + (size_t)2304 * 768;            // [768][768]
  short* Qb    = WoutT + (size_t)768 * 768;             // [96][1024][64]
  short* Kb    = Qb    + (size_t)96 * 1024 * 64;        // [96][1024][64]
  short* VTb   = Kb    + (size_t)96 * 1024 * 64;        // [96][64][1024] perm'd
  short* AO    = VTb   + (size_t)96 * 1024 * 64;        // [8192][768]
  short* xbf   = AO;                                    // alias (see above)

  prep_kernel<<<dim3(3072 + 1728 + 576), 256, 0, stream>>>(
      x, xbf, w_in, WinT, w_out, WoutT);

  gemm_tile<0><<<dim3(8192 / 128, 2304 / 128), 256, 0, stream>>>(
      xbf, WinT, 768, Qb, Kb, VTb, nullptr, nullptr);

  attn_kernel<<<dim3(768), 256, 0, stream>>>(Qb, Kb, VTb, AO);

  gemm_tile<1><<<dim3(8192 / 128, 768 / 128), 256, 0, stream>>>(
      AO, WoutT, 768, nullptr, nullptr, nullptr, b_out, out);
}

// Round 14
// 120.034 us; speedup vs baseline: 1.1788x; 1.0011x over previous
//
#include <hip/hip_runtime.h>

// ---------------------------------------------------------------------------
// MultiHeadedAttention: x[8,1024,768] @ w_in[768,2304] -> qkv -> 12-head attn
// (scale = 768^-0.5) -> concat -> @ w_out[768,768] + b_out. f32 in/out,
// bf16 MFMA internally. R14 = R13 + attn qh-pipelined epilogue: PV(qh0)
// issued BEFORE softmax(qh1) so its MFMAs run under qh1's VALU chain (T15
// mechanism), and 4-way-parallel rsum partials (was a 16-deep float chain).
// ---------------------------------------------------------------------------

using short8 = __attribute__((ext_vector_type(8))) short;  // 8 bf16 (4 VGPR)
using f32x4  = __attribute__((ext_vector_type(4))) float;  // MFMA acc

#define MFMA_B16(a, b, c) __builtin_amdgcn_mfma_f32_16x16x32_bf16((a), (b), (c), 0, 0, 0)

typedef const __attribute__((address_space(1))) void* gvoid_p;
typedef __attribute__((address_space(3))) void* lvoid_p;

constexpr int   kDim   = 768;
constexpr int   kHeads = 12;
constexpr int   kSeq   = 1024;
constexpr float kScale = 0.03608439182435161f;             // 768^-0.5 (full dim)
constexpr float kQSc   = kScale * 1.4426950408889634f;     // fold log2(e) into Q

__device__ __forceinline__ short f2bf(float f) {  // RNE f32 -> bf16 bits
  unsigned u = __float_as_uint(f);
  u += 0x7FFFu + ((u >> 16) & 1u);
  return (short)(u >> 16);
}
__device__ __forceinline__ unsigned cvt_pk_bf16(float lo, float hi) {
  unsigned r;
  asm("v_cvt_pk_bf16_f32 %0, %1, %2" : "=v"(r) : "v"(lo), "v"(hi));
  return r;
}
union U8 { unsigned u[4]; short8 s; };

// ---------- merged prep: x cast (blocks 0..3071), w_in^T (next 1728),
// ----------              w_out^T (last 576). One launch instead of three.
__global__ __launch_bounds__(256) void prep_kernel(const float* __restrict__ x,
                                                   short* __restrict__ xbf,
                                                   const float* __restrict__ w_in,
                                                   short* __restrict__ WinT,
                                                   const float* __restrict__ w_out,
                                                   short* __restrict__ WoutT) {
  __shared__ float tile[32][33];
  const int bid = blockIdx.x;
  if (bid < 3072) {  // cast: one short8 per thread
    const int i = bid * 256 + threadIdx.x;
    float4 a = ((const float4*)x)[i * 2];
    float4 b = ((const float4*)x)[i * 2 + 1];
    short8 s;
    s[0] = f2bf(a.x); s[1] = f2bf(a.y); s[2] = f2bf(a.z); s[3] = f2bf(a.w);
    s[4] = f2bf(b.x); s[5] = f2bf(b.y); s[6] = f2bf(b.z); s[7] = f2bf(b.w);
    ((short8*)xbf)[i] = s;
    return;
  }
  // transpose+cvt: out[c][r] = bf16(in[r][c])
  const float* in; short* out; int R, C, bx, by;
  if (bid < 3072 + 1728) {
    const int b2 = bid - 3072;
    in = w_in; out = WinT; R = 768; C = 2304; bx = b2 % 72; by = b2 / 72;
  } else {
    const int b2 = bid - 4800;
    in = w_out; out = WoutT; R = 768; C = 768; bx = b2 % 24; by = b2 / 24;
  }
  const int c0 = bx * 32, r0 = by * 32;
  const int tx = threadIdx.x & 31, ty = threadIdx.x >> 5;
#pragma unroll
  for (int i = 0; i < 32; i += 8)
    tile[ty + i][tx] = in[(size_t)(r0 + ty + i) * C + c0 + tx];
  __syncthreads();
#pragma unroll
  for (int i = 0; i < 32; i += 8)
    out[(size_t)(c0 + ty + i) * R + r0 + tx] = f2bf(tile[tx][ty + i]);
}

// ---------- 128x128 MFMA GEMM, BK=32, 4 waves, 3-buf 2-deep counted-vmcnt --
// (exact R8/R13 structure — measured best; do not touch)
template <int EPI>
__global__ __launch_bounds__(256) void gemm_tile(const short* __restrict__ A,
                                                 const short* __restrict__ BT,
                                                 int Kd,
                                                 short* __restrict__ Qb,
                                                 short* __restrict__ Kb,
                                                 short* __restrict__ VTb,
                                                 const float* __restrict__ bias,
                                                 float* __restrict__ outF) {
  __shared__ short As[3][128 * 32];
  __shared__ short Bs[3][128 * 32];

  const int tid  = threadIdx.x;
  const int lane = tid & 63, w = tid >> 6;
  const int L = lane & 15, g = lane >> 4;
  const int wr = w >> 1, wc = w & 1;
  const int m0 = blockIdx.x * 128, n0 = blockIdx.y * 128;

  const int r4 = lane >> 2;        // row within 16-row chunk
  const int c8 = (lane & 3) * 8;   // k-col (shorts)

  auto stage = [&](int buf, int k0) {  // 4 gload_lds per wave (vmcnt +4)
#pragma unroll
    for (int c = 0; c < 2; ++c) {
      const short* ag = A  + (size_t)(m0 + w * 32 + c * 16 + r4) * Kd + k0 + c8;
      const short* bg = BT + (size_t)(n0 + w * 32 + c * 16 + r4) * Kd + k0 + c8;
      __builtin_amdgcn_global_load_lds((gvoid_p)ag, (lvoid_p)&As[buf][(w * 2 + c) * 512], 16, 0, 0);
      __builtin_amdgcn_global_load_lds((gvoid_p)bg, (lvoid_p)&Bs[buf][(w * 2 + c) * 512], 16, 0, 0);
    }
  };

  f32x4 acc[4][4] = {};

  stage(0, 0);
  stage(1, 32);

  const int NT = Kd / 32;
  for (int t = 0; t < NT; ++t) {
    const int cur = t % 3;
    if (t + 2 < NT) stage((t + 2) % 3, (t + 2) * 32);

    // wait for tile t only; tiles t+1, t+2 (8 loads) stay in flight
    if (t + 2 < NT)      asm volatile("s_waitcnt vmcnt(8)" ::: "memory");
    else if (t + 1 < NT) asm volatile("s_waitcnt vmcnt(4)" ::: "memory");
    else                 asm volatile("s_waitcnt vmcnt(0)" ::: "memory");
    __builtin_amdgcn_s_barrier();  // all waves' tile-t loads landed

    short8 af[4], bfr[4];
#pragma unroll
    for (int mi = 0; mi < 4; ++mi)
      af[mi] = *(const short8*)&As[cur][(wr * 64 + mi * 16 + L) * 32 + g * 8];
#pragma unroll
    for (int ni = 0; ni < 4; ++ni)
      bfr[ni] = *(const short8*)&Bs[cur][(wc * 64 + ni * 16 + L) * 32 + g * 8];
#pragma unroll
    for (int mi = 0; mi < 4; ++mi)
#pragma unroll
      for (int ni = 0; ni < 4; ++ni)
        acc[mi][ni] = MFMA_B16(af[mi], bfr[ni], acc[mi][ni]);

    asm volatile("" ::: "memory");
    __builtin_amdgcn_s_barrier();  // reads done before next stage overwrites
  }

  if (EPI == 0) {
    const int t3 = n0 / kDim;  // 0:Q 1:K 2:V (uniform per block; 768 = 6*128)
#pragma unroll
    for (int mi = 0; mi < 4; ++mi) {
#pragma unroll
      for (int ni = 0; ni < 4; ++ni) {
        const int gcol = n0 + wc * 64 + ni * 16 + L;
        const int hd = gcol % kDim;
        const int h = hd >> 6, d = hd & 63;
        if (t3 == 2) {
          // V^T with key-permuted 64-blocks: position p stores key s where
          // p = 32(s>>5) + 8((s>>2)&3) + 4((s>>4)&1) + (s&3). The 4 r-values
          // are consecutive keys (s%4==0) -> consecutive positions -> 8B store.
          const int grow = m0 + wr * 64 + mi * 16 + 4 * g;
          const int b = grow >> 10, seq = grow & 1023;
          const int bh = b * kHeads + h;
          const int s6 = seq & 63;  // multiple of 4
          const int p  = 32 * (s6 >> 5) + 8 * ((s6 >> 2) & 3) + 4 * ((s6 >> 4) & 1);
          const int seqp = (seq & ~63) | p;
          uint2 d2;
          d2.x = cvt_pk_bf16(acc[mi][ni][0], acc[mi][ni][1]);
          d2.y = cvt_pk_bf16(acc[mi][ni][2], acc[mi][ni][3]);
          *(uint2*)&VTb[((size_t)bh * 64 + d) * kSeq + seqp] = d2;
        } else {
#pragma unroll
          for (int r = 0; r < 4; ++r) {
            const int grow = m0 + wr * 64 + mi * 16 + 4 * g + r;  // b*1024+seq
            const int b = grow >> 10, seq = grow & 1023;
            const int bh = b * kHeads + h;
            if (t3 == 0) Qb[((size_t)bh * kSeq + seq) * 64 + d] = f2bf(acc[mi][ni][r] * kQSc);
            else         Kb[((size_t)bh * kSeq + seq) * 64 + d] = f2bf(acc[mi][ni][r]);
          }
        }
      }
    }
  } else {
#pragma unroll
    for (int ni = 0; ni < 4; ++ni) {
      const int gcol = n0 + wc * 64 + ni * 16 + L;
      const float bv = bias[gcol];
#pragma unroll
      for (int mi = 0; mi < 4; ++mi) {
#pragma unroll
        for (int r = 0; r < 4; ++r) {
          const int grow = m0 + wr * 64 + mi * 16 + 4 * g + r;
          outF[(size_t)grow * kDim + gcol] = acc[mi][ni][r] + bv;
        }
      }
    }
  }
}

// ---------- flash attention (R13 + qh-pipelined SM/PV) ----------------------
__global__ __launch_bounds__(256) void attn_kernel(const short* __restrict__ Qb,
                                                   const short* __restrict__ Kb,
                                                   const short* __restrict__ VTb,
                                                   short* __restrict__ AO) {
  __shared__ short Ks[2][64 * 72];   // [key][d]
  __shared__ short VTs[2][64 * 72];  // [d][key-permuted]

  const int tid  = threadIdx.x;
  const int lane = tid & 63, w = tid >> 6;
  const int L = lane & 15, g = lane >> 4;
  const int id = blockIdx.x;
  const int bh = id % 96, qc = id / 96;
  const int q0 = qc * 128 + w * 32;

  const short* Qbase = Qb  + (size_t)bh * kSeq * 64;
  const short* Kbase = Kb  + (size_t)bh * kSeq * 64;
  const short* Vbase = VTb + (size_t)bh * 64 * kSeq;

  short8 qf[2][2];  // Q (pre-scaled by kQSc) as B-operand, resident in regs
#pragma unroll
  for (int qh = 0; qh < 2; ++qh) {
    const short* qp = Qbase + (size_t)(q0 + qh * 16 + L) * 64 + g * 8;
    qf[qh][0] = *(const short8*)qp;
    qf[qh][1] = *(const short8*)(qp + 32);
  }

  f32x4 o[2][4] = {};
  float m_[2] = {-1e30f, -1e30f};  // per-query running max (replicated over g)
  float l_[2] = {0.f, 0.f};        // per-LANE partial sum (reduced at end)

  const int srow = tid >> 2, sc0 = (tid & 3) * 16;  // staging: 16 elems/thread

  {  // prologue: stage tile 0 (V rows copied verbatim — perm is within blocks)
    const short* ksrc = Kbase + (size_t)srow * 64 + sc0;
    const short* vsrc = Vbase + (size_t)srow * kSeq + sc0;
    uint4 k0 = ((const uint4*)ksrc)[0], k1 = ((const uint4*)ksrc)[1];
    uint4 v0 = ((const uint4*)vsrc)[0], v1 = ((const uint4*)vsrc)[1];
    *(uint4*)&Ks[0][srow * 72 + sc0]      = k0;
    *(uint4*)&Ks[0][srow * 72 + sc0 + 8]  = k1;
    *(uint4*)&VTs[0][srow * 72 + sc0]     = v0;
    *(uint4*)&VTs[0][srow * 72 + sc0 + 8] = v1;
  }
  __syncthreads();

  for (int t = 0; t < kSeq / 64; ++t) {
    const int cur = t & 1;
    const bool pf = (t + 1 < kSeq / 64);

    // ---- issue next-tile loads early (T14 async split) ----
    uint4 kr0, kr1, vr0, vr1;
    if (pf) {
      const int kv1 = (t + 1) * 64;
      const short* ksrc = Kbase + (size_t)(kv1 + srow) * 64 + sc0;
      const short* vsrc = Vbase + (size_t)srow * kSeq + kv1 + sc0;
      kr0 = ((const uint4*)ksrc)[0]; kr1 = ((const uint4*)ksrc)[1];
      vr0 = ((const uint4*)vsrc)[0]; vr1 = ((const uint4*)vsrc)[1];
    }

    // ---- K fragments (A-operand) + V fragments (B-operand, pre-permuted) --
    short8 kf[4][2];
#pragma unroll
    for (int nf = 0; nf < 4; ++nf) {
      const short* kp = &Ks[cur][(nf * 16 + L) * 72 + g * 8];
      kf[nf][0] = *(const short8*)kp;
      kf[nf][1] = *(const short8*)(kp + 32);
    }
    short8 vb[4][2];  // hoisted: ds latency hides under QK below
#pragma unroll
    for (int nf = 0; nf < 4; ++nf) {
      const short* vrow = &VTs[cur][(nf * 16 + L) * 72];
      vb[nf][0] = *(const short8*)&vrow[g * 8];
      vb[nf][1] = *(const short8*)&vrow[32 + g * 8];
    }

    // ---- BOTH q-halves' S^T = K @ Q^T issued back-to-back (32 MFMAs) ----
    f32x4 s2[2][4];
    __builtin_amdgcn_s_setprio(1);
#pragma unroll
    for (int qh = 0; qh < 2; ++qh) {
#pragma unroll
      for (int nf = 0; nf < 4; ++nf) {
        f32x4 z = {};
        z = MFMA_B16(kf[nf][0], qf[qh][0], z);
        s2[qh][nf] = MFMA_B16(kf[nf][1], qf[qh][1], z);
      }
    }
    __builtin_amdgcn_s_setprio(0);

    // ---- pipelined per-qh: SM(qh) then immediately PV(qh), so PV(qh0)'s
    // ---- MFMAs (matrix pipe) run under SM(qh1)'s VALU chain (T15) --------
#pragma unroll
    for (int qh = 0; qh < 2; ++qh) {
      f32x4* s = s2[qh];
      float x0 = fmaxf(fmaxf(s[0][0], s[0][1]), fmaxf(s[0][2], s[0][3]));
      float x1 = fmaxf(fmaxf(s[1][0], s[1][1]), fmaxf(s[1][2], s[1][3]));
      float x2 = fmaxf(fmaxf(s[2][0], s[2][1]), fmaxf(s[2][2], s[2][3]));
      float x3 = fmaxf(fmaxf(s[3][0], s[3][1]), fmaxf(s[3][2], s[3][3]));
      const float mt4 = fmaxf(fmaxf(x0, x1), fmaxf(x2, x3));

      if (__any(mt4 > m_[qh] + 8.0f)) {  // wave-uniform branch (rare)
        float mt = fmaxf(mt4, __shfl_xor(mt4, 16, 64));
        mt = fmaxf(mt, __shfl_xor(mt, 32, 64));          // per-query true max
        const float mnew = fmaxf(m_[qh], mt);
        const float al = __builtin_amdgcn_exp2f(m_[qh] - mnew);
        m_[qh] = mnew;
        l_[qh] *= al;  // per-lane partial: al is query-uniform across g
        float alr[4];
#pragma unroll
        for (int r = 0; r < 4; ++r) alr[r] = __shfl(al, 4 * g + r, 64);
#pragma unroll
        for (int nf = 0; nf < 4; ++nf)
#pragma unroll
          for (int r = 0; r < 4; ++r) o[qh][nf][r] *= alr[r];
      }

      // 4-way parallel rsum partials (was a 16-deep dependent float chain)
      float rs0 = 0.f, rs1 = 0.f, rs2 = 0.f, rs3 = 0.f;
#pragma unroll
      for (int nf = 0; nf < 4; ++nf) {
        float p0 = __builtin_amdgcn_exp2f(s[nf][0] - m_[qh]);
        float p1 = __builtin_amdgcn_exp2f(s[nf][1] - m_[qh]);
        float p2 = __builtin_amdgcn_exp2f(s[nf][2] - m_[qh]);
        float p3 = __builtin_amdgcn_exp2f(s[nf][3] - m_[qh]);
        s[nf][0] = p0; s[nf][1] = p1; s[nf][2] = p2; s[nf][3] = p3;
        rs0 += p0; rs1 += p1; rs2 += p2; rs3 += p3;
      }
      l_[qh] += (rs0 + rs1) + (rs2 + rs3);  // per-lane partial

      U8 t0, t1;
      t0.u[0] = cvt_pk_bf16(s[0][0], s[0][1]);
      t0.u[1] = cvt_pk_bf16(s[0][2], s[0][3]);
      t0.u[2] = cvt_pk_bf16(s[1][0], s[1][1]);
      t0.u[3] = cvt_pk_bf16(s[1][2], s[1][3]);
      t1.u[0] = cvt_pk_bf16(s[2][0], s[2][1]);
      t1.u[1] = cvt_pk_bf16(s[2][2], s[2][3]);
      t1.u[2] = cvt_pk_bf16(s[3][0], s[3][1]);
      t1.u[3] = cvt_pk_bf16(s[3][2], s[3][3]);

      // PV(qh) immediately — qh=0's MFMAs overlap qh=1's softmax VALU
      __builtin_amdgcn_s_setprio(1);
#pragma unroll
      for (int nf = 0; nf < 4; ++nf) {
        o[qh][nf] = MFMA_B16(t0.s, vb[nf][0], o[qh][nf]);
        o[qh][nf] = MFMA_B16(t1.s, vb[nf][1], o[qh][nf]);
      }
      __builtin_amdgcn_s_setprio(0);
    }

    // ---- write prefetched tile into other buffer; one barrier per tile ----
    if (pf) {
      *(uint4*)&Ks[cur ^ 1][srow * 72 + sc0]      = kr0;
      *(uint4*)&Ks[cur ^ 1][srow * 72 + sc0 + 8]  = kr1;
      *(uint4*)&VTs[cur ^ 1][srow * 72 + sc0]     = vr0;
      *(uint4*)&VTs[cur ^ 1][srow * 72 + sc0 + 8] = vr1;
    }
    __syncthreads();
  }

  // ---- finalize: reduce l across g-groups ONCE, O /= l, store ----
  const int b = bh / kHeads, h = bh % kHeads;
#pragma unroll
  for (int qh = 0; qh < 2; ++qh) {
    float ls = l_[qh] + __shfl_xor(l_[qh], 16, 64);
    ls += __shfl_xor(ls, 32, 64);  // full per-query sum
    float lq[4];
#pragma unroll
    for (int r = 0; r < 4; ++r) lq[r] = __shfl(ls, 4 * g + r, 64);
    short* aop = AO + ((size_t)(b * kSeq) + q0 + qh * 16) * kDim + h * 64;
#pragma unroll
    for (int r = 0; r < 4; ++r) {
      const float inv = 1.0f / lq[r];
#pragma unroll
      for (int nf = 0; nf < 4; ++nf)
        aop[(size_t)(4 * g + r) * kDim + nf * 16 + L] = f2bf(o[qh][nf][r] * inv);
    }
  }
}

// ---------------------------------------------------------------------------
extern "C" void kernel_launch(void* const* d_in, const int* in_sizes, int n_in,
                              void* d_out, int out_size, void* d_ws, size_t ws_size,
                              hipStream_t stream) {
  const float* x     = (const float*)d_in[0];
  const float* w_in  = (const float*)d_in[1];
  const float* w_out = (const float*)d_in[2];
  const float* b_out = (const float*)d_in[3];
  float* out = (float*)d_out;

  // workspace (bf16 as short). xbf aliases AO: xbf dead before attn writes AO.
  short* WinT  = (short*)d_ws;                          // [2304][768]
  short* WoutT = WinT  + (size_t)2304 * 768;            // [768][768]
  short* Qb    = WoutT + (size_t)768 * 768;             // [96][1024][64]
  short* Kb    = Qb    + (size_t)96 * 1024 * 64;        // [96][1024][64]
  short* VTb   = Kb    + (size_t)96 * 1024 * 64;        // [96][64][1024] perm'd
  short* AO    = VTb   + (size_t)96 * 1024 * 64;        // [8192][768]
  short* xbf   = AO;                                    // alias (see above)

  prep_kernel<<<dim3(3072 + 1728 + 576), 256, 0, stream>>>(
      x, xbf, w_in, WinT, w_out, WoutT);

  gemm_tile<0><<<dim3(8192 / 128, 2304 / 128), 256, 0, stream>>>(
      xbf, WinT, 768, Qb, Kb, VTb, nullptr, nullptr);

  attn_kernel<<<dim3(768), 256, 0, stream>>>(Qb, Kb, VTb, AO);

  gemm_tile<1><<<dim3(8192 / 128, 768 / 128), 256, 0, stream>>>(
      AO, WoutT, 768, nullptr, nullptr, nullptr, b_out, out);
}